// Round 2
// baseline (6762.842 us; speedup 1.0000x reference)
//
#include <hip/hip_runtime.h>
#include <stdint.h>

#define BB 2
#define NN 4096
#define KNB 20
#define DD 128
#define PHH 8
#define AHH 512
#define BN (BB*NN)

// ---------------- linear1: h = x @ W1.T + b1 ----------------
__global__ void k_lin1(const float* __restrict__ x, const float* __restrict__ W1,
                       const float* __restrict__ b1, float* __restrict__ h) {
    int p = blockIdx.x;      // point 0..BN-1
    int t = threadIdx.x;     // channel 0..127
    float x0 = x[p*3+0], x1 = x[p*3+1], x2 = x[p*3+2];
    float acc = b1[t] + x0*W1[t*3+0] + x1*W1[t*3+1] + x2*W1[t*3+2];
    h[(size_t)p*DD + t] = acc;
}

// ---------------- linear2 + qkv ----------------
__global__ void k_qkv(const float* __restrict__ h, const float* __restrict__ W2,
                      const float* __restrict__ b2, const float* __restrict__ Wqkv,
                      float* __restrict__ qf, float* __restrict__ kf, float* __restrict__ vf) {
    __shared__ __align__(16) float hrow[DD];
    __shared__ __align__(16) float h1row[DD];
    int p = blockIdx.x, t = threadIdx.x;
    hrow[t] = h[(size_t)p*DD + t];
    __syncthreads();
    float acc = b2[t];
    const float* w = W2 + (size_t)t*DD;
    for (int d = 0; d < DD; d += 4) {
        float4 w4 = *(const float4*)(w + d);
        acc += hrow[d]*w4.x + hrow[d+1]*w4.y + hrow[d+2]*w4.z + hrow[d+3]*w4.w;
    }
    h1row[t] = acc;
    __syncthreads();
    for (int r = 0; r < 3; ++r) {
        const float* wr = Wqkv + (size_t)(r*DD + t)*DD;
        float a2 = 0.f;
        for (int d = 0; d < DD; d += 4) {
            float4 w4 = *(const float4*)(wr + d);
            a2 += h1row[d]*w4.x + h1row[d+1]*w4.y + h1row[d+2]*w4.z + h1row[d+3]*w4.w;
        }
        float* dst = (r == 0) ? qf : (r == 1) ? kf : vf;
        dst[(size_t)p*DD + t] = a2;
    }
}

// ---------------- KNN: top-20 smallest squared distance ----------------
__global__ __launch_bounds__(256) void k_knn(const float* __restrict__ pos, int* __restrict__ idx) {
    const int TC = 512;
    __shared__ float px[TC], py[TC], pz[TC];
    int p = blockIdx.x*256 + threadIdx.x;   // query point (global)
    int b = p / NN;
    float qx = pos[p*3+0], qy = pos[p*3+1], qz = pos[p*3+2];
    float bd[KNB]; int bi[KNB];
    #pragma unroll
    for (int i = 0; i < KNB; ++i) { bd[i] = 3.4e38f; bi[i] = -1; }
    const float* pb = pos + (size_t)b*NN*3;
    for (int tile = 0; tile < NN; tile += TC) {
        for (int c = threadIdx.x; c < TC; c += 256) {
            int j = tile + c;
            px[c] = pb[j*3+0]; py[c] = pb[j*3+1]; pz[c] = pb[j*3+2];
        }
        __syncthreads();
        float worst = bd[KNB-1];
        for (int c = 0; c < TC; ++c) {
            float dx = qx - px[c], dy = qy - py[c], dz = qz - pz[c];
            float d2 = dx*dx + dy*dy;
            d2 = d2 + dz*dz;
            if (d2 < worst) {                 // strict <: ties keep earlier index (matches top_k)
                int j = tile + c;
                int pp = KNB-1;
                while (pp > 0 && bd[pp-1] > d2) { bd[pp] = bd[pp-1]; bi[pp] = bi[pp-1]; --pp; }
                bd[pp] = d2; bi[pp] = j;
                worst = bd[KNB-1];
            }
        }
        __syncthreads();
    }
    for (int i = 0; i < KNB; ++i) idx[(size_t)p*KNB + i] = bi[i];
}

// ---------------- fused pos-MLP + attn-MLP + softmax + aggregate ----------------
__global__ __launch_bounds__(256) void k_attn(
        const float* __restrict__ pos,
        const float* __restrict__ qf, const float* __restrict__ kf, const float* __restrict__ vf,
        const int* __restrict__ idx,
        const float* __restrict__ Wp1, const float* __restrict__ bp1,
        const float* __restrict__ Wp2, const float* __restrict__ bp2,
        const float* __restrict__ Wa1, const float* __restrict__ ba1,
        const float* __restrict__ Wa2, const float* __restrict__ ba2,
        float* __restrict__ agg) {
    __shared__ __align__(16) float qrow[DD];
    __shared__ __align__(16) float ph[KNB][PHH];
    __shared__ __align__(16) float X[KNB][DD];     // x = q - kn + pe;  reused as SIM after phase C
    __shared__ __align__(16) float VPE[KNB][DD];   // v + pe
    __shared__ __align__(16) float T[KNB][AHH];    // relu hidden
    __shared__ int nidx[KNB];

    int p = blockIdx.x;
    int b = p / NN;
    int tid = threadIdx.x;

    if (tid < DD) qrow[tid] = qf[(size_t)p*DD + tid];
    if (tid < KNB) nidx[tid] = idx[(size_t)p*KNB + tid];
    __syncthreads();

    // A1: pos-MLP hidden (20 neighbors x 8)
    if (tid < KNB*PHH) {
        int kk = tid / PHH, jj = tid % PHH;
        int j = nidx[kk];
        const float* pq = pos + (size_t)p*3;
        const float* pn = pos + (size_t)(b*NN + j)*3;
        float r0 = pq[0] - pn[0];
        float r1 = pq[1] - pn[1];
        float r2 = pq[2] - pn[2];
        float a = bp1[jj] + r0*Wp1[jj*3+0] + r1*Wp1[jj*3+1] + r2*Wp1[jj*3+2];
        ph[kk][jj] = fmaxf(a, 0.f);
    }
    __syncthreads();

    // A2: pe, X, VPE  (20*128 elems, 10 iters of 256)
    for (int it = 0; it < (KNB*DD)/256; ++it) {
        int lin = it*256 + tid;
        int kk = lin / DD, d = lin % DD;
        int j = nidx[kk];
        const float* w = Wp2 + (size_t)d*PHH;
        float pe = bp2[d];
        #pragma unroll
        for (int jj = 0; jj < PHH; ++jj) pe += ph[kk][jj] * w[jj];
        float kv = kf[(size_t)(b*NN + j)*DD + d];
        float vv = vf[(size_t)(b*NN + j)*DD + d];
        X[kk][d] = qrow[d] - kv + pe;
        VPE[kk][d] = vv + pe;
    }
    __syncthreads();

    // B: T[kk][a] = relu(X[kk] . Wa1[a] + ba1[a]);  each thread owns rows tid and tid+256
    {
        float acc1[KNB], acc2[KNB];
        #pragma unroll
        for (int i = 0; i < KNB; ++i) { acc1[i] = 0.f; acc2[i] = 0.f; }
        const float* w1 = Wa1 + (size_t)tid*DD;
        const float* w2 = Wa1 + (size_t)(tid+256)*DD;
        for (int d = 0; d < DD; d += 4) {
            float4 u1 = *(const float4*)(w1 + d);
            float4 u2 = *(const float4*)(w2 + d);
            #pragma unroll
            for (int kk = 0; kk < KNB; ++kk) {
                float4 xv = *(const float4*)&X[kk][d];
                acc1[kk] += xv.x*u1.x + xv.y*u1.y + xv.z*u1.z + xv.w*u1.w;
                acc2[kk] += xv.x*u2.x + xv.y*u2.y + xv.z*u2.z + xv.w*u2.w;
            }
        }
        float bb1 = ba1[tid], bb2 = ba1[tid+256];
        #pragma unroll
        for (int kk = 0; kk < KNB; ++kk) {
            T[kk][tid]     = fmaxf(acc1[kk] + bb1, 0.f);
            T[kk][tid+256] = fmaxf(acc2[kk] + bb2, 0.f);
        }
    }
    __syncthreads();

    // C: SIM[kk][d] = T[kk] . Wa2[d] + ba2[d];  thread = (d, kk-half)
    {
        int d = tid & 127, g = tid >> 7;
        float acc[10];
        #pragma unroll
        for (int i = 0; i < 10; ++i) acc[i] = 0.f;
        const float* w = Wa2 + (size_t)d*AHH;
        for (int a = 0; a < AHH; a += 4) {
            float4 u = *(const float4*)(w + a);
            #pragma unroll
            for (int i = 0; i < 10; ++i) {
                float4 tv = *(const float4*)&T[g*10 + i][a];
                acc[i] += tv.x*u.x + tv.y*u.y + tv.z*u.z + tv.w*u.w;
            }
        }
        float bb = ba2[d];
        #pragma unroll
        for (int i = 0; i < 10; ++i) X[g*10 + i][d] = acc[i] + bb;   // X reused as SIM
    }
    __syncthreads();

    // D: softmax over kk per channel + aggregate
    if (tid < DD) {
        int d = tid;
        float m = -3.4e38f;
        #pragma unroll
        for (int kk = 0; kk < KNB; ++kk) m = fmaxf(m, X[kk][d]);
        float e[KNB]; float s = 0.f;
        #pragma unroll
        for (int kk = 0; kk < KNB; ++kk) { e[kk] = __expf(X[kk][d] - m); s += e[kk]; }
        float inv = 1.f / s;
        float a = 0.f;
        #pragma unroll
        for (int kk = 0; kk < KNB; ++kk) a += e[kk]*inv*VPE[kk][d];
        agg[(size_t)p*DD + d] = a;
    }
}

// ---------------- out = h + agg @ W3.T + b3 ----------------
__global__ void k_out(const float* __restrict__ agg, const float* __restrict__ h,
                      const float* __restrict__ W3, const float* __restrict__ b3,
                      float* __restrict__ out) {
    __shared__ __align__(16) float arow[DD];
    int p = blockIdx.x, t = threadIdx.x;
    arow[t] = agg[(size_t)p*DD + t];
    __syncthreads();
    const float* w = W3 + (size_t)t*DD;
    float acc = b3[t];
    for (int d = 0; d < DD; d += 4) {
        float4 w4 = *(const float4*)(w + d);
        acc += arow[d]*w4.x + arow[d+1]*w4.y + arow[d+2]*w4.z + arow[d+3]*w4.w;
    }
    out[(size_t)p*DD + t] = acc + h[(size_t)p*DD + t];
}

extern "C" void kernel_launch(void* const* d_in, const int* in_sizes, int n_in,
                              void* d_out, int out_size, void* d_ws, size_t ws_size,
                              hipStream_t stream) {
    const float* x    = (const float*)d_in[0];
    const float* pos  = (const float*)d_in[1];
    const float* W1   = (const float*)d_in[2];
    const float* b1   = (const float*)d_in[3];
    const float* W2   = (const float*)d_in[4];
    const float* b2   = (const float*)d_in[5];
    const float* W3   = (const float*)d_in[6];
    const float* b3   = (const float*)d_in[7];
    const float* Wqkv = (const float*)d_in[8];
    const float* Wp1  = (const float*)d_in[9];
    const float* bp1  = (const float*)d_in[10];
    const float* Wp2  = (const float*)d_in[11];
    const float* bp2  = (const float*)d_in[12];
    const float* Wa1  = (const float*)d_in[13];
    const float* ba1  = (const float*)d_in[14];
    const float* Wa2  = (const float*)d_in[15];
    const float* ba2  = (const float*)d_in[16];

    float* ws  = (float*)d_ws;
    float* h   = ws;
    float* qf  = ws + 1*(size_t)BN*DD;
    float* kf  = ws + 2*(size_t)BN*DD;
    float* vf  = ws + 3*(size_t)BN*DD;
    float* agg = ws + 4*(size_t)BN*DD;
    int*   idx = (int*)(ws + 5*(size_t)BN*DD);

    k_lin1<<<BN, DD, 0, stream>>>(x, W1, b1, h);
    k_qkv <<<BN, DD, 0, stream>>>(h, W2, b2, Wqkv, qf, kf, vf);
    k_knn <<<BN/256, 256, 0, stream>>>(pos, idx);
    k_attn<<<BN, 256, 0, stream>>>(pos, qf, kf, vf, idx,
                                   Wp1, bp1, Wp2, bp2, Wa1, ba1, Wa2, ba2, agg);
    k_out <<<BN, DD, 0, stream>>>(agg, h, W3, b3, (float*)d_out);
}

// Round 3
// 1392.957 us; speedup vs baseline: 4.8550x; 4.8550x over previous
//
#include <hip/hip_runtime.h>
#include <stdint.h>

#define BB 2
#define NN 4096
#define KNB 20
#define DD 128
#define PHH 8
#define AHH 512
#define BN (BB*NN)

__device__ __forceinline__ uint32_t umin32(uint32_t a, uint32_t b) { return a < b ? a : b; }
__device__ __forceinline__ uint32_t umax32(uint32_t a, uint32_t b) { return a > b ? a : b; }

// ---------------- linear1: h = x @ W1.T + b1 ----------------
__global__ void k_lin1(const float* __restrict__ x, const float* __restrict__ W1,
                       const float* __restrict__ b1, float* __restrict__ h) {
    int p = blockIdx.x;      // point 0..BN-1
    int t = threadIdx.x;     // channel 0..127
    float x0 = x[p*3+0], x1 = x[p*3+1], x2 = x[p*3+2];
    float acc = b1[t] + x0*W1[t*3+0] + x1*W1[t*3+1] + x2*W1[t*3+2];
    h[(size_t)p*DD + t] = acc;
}

// ---------------- linear2 + qkv ----------------
__global__ void k_qkv(const float* __restrict__ h, const float* __restrict__ W2,
                      const float* __restrict__ b2, const float* __restrict__ Wqkv,
                      float* __restrict__ qf, float* __restrict__ kf, float* __restrict__ vf) {
    __shared__ __align__(16) float hrow[DD];
    __shared__ __align__(16) float h1row[DD];
    int p = blockIdx.x, t = threadIdx.x;
    hrow[t] = h[(size_t)p*DD + t];
    __syncthreads();
    float acc = b2[t];
    const float* w = W2 + (size_t)t*DD;
    for (int d = 0; d < DD; d += 4) {
        float4 w4 = *(const float4*)(w + d);
        acc += hrow[d]*w4.x + hrow[d+1]*w4.y + hrow[d+2]*w4.z + hrow[d+3]*w4.w;
    }
    h1row[t] = acc;
    __syncthreads();
    for (int r = 0; r < 3; ++r) {
        const float* wr = Wqkv + (size_t)(r*DD + t)*DD;
        float a2 = 0.f;
        for (int d = 0; d < DD; d += 4) {
            float4 w4 = *(const float4*)(wr + d);
            a2 += h1row[d]*w4.x + h1row[d+1]*w4.y + h1row[d+2]*w4.z + h1row[d+3]*w4.w;
        }
        float* dst = (r == 0) ? qf : (r == 1) ? kf : vf;
        dst[(size_t)p*DD + t] = a2;
    }
}

// ---------------- KNN: one wave per query, register top-20 via packed keys ----------------
// key = (f32bits(d2) & 0xFFFFF000) | j  — d2>=0 so uint order == float order; idx in 12 LSBs
__global__ __launch_bounds__(256) void k_knn(const float* __restrict__ pos, int* __restrict__ idx) {
    int wid  = threadIdx.x >> 6;
    int lane = threadIdx.x & 63;
    int p = blockIdx.x*4 + wid;            // query point (global), 1 wave per query
    int b = p >> 12;                       // p / NN
    float qx = pos[p*3+0], qy = pos[p*3+1], qz = pos[p*3+2];
    const float* pb = pos + (size_t)b*NN*3;

    uint32_t bk[KNB];
    #pragma unroll
    for (int i = 0; i < KNB; ++i) bk[i] = 0xFFFFFFFFu;

    for (int i = 0; i < NN/64; ++i) {
        int j = i*64 + lane;               // coalesced across lanes
        float dx = qx - pb[j*3+0];
        float dy = qy - pb[j*3+1];
        float dz = qz - pb[j*3+2];
        float d2 = dx*dx + dy*dy + dz*dz;
        uint32_t key = (__float_as_uint(d2) & 0xFFFFF000u) | (uint32_t)j;
        if (key < bk[KNB-1]) {             // bubble-insert, fully static indices -> VGPRs
            uint32_t c = key;
            #pragma unroll
            for (int t = 0; t < KNB; ++t) {
                uint32_t lo = umin32(c, bk[t]);
                uint32_t hi = umax32(c, bk[t]);
                bk[t] = lo; c = hi;
            }
        }
    }

    // merge 64 lane-local sorted lists -> global top-20 (keys unique: j disjoint per lane)
    for (int r = 0; r < KNB; ++r) {
        uint32_t m = bk[0];
        #pragma unroll
        for (int s = 1; s < 64; s <<= 1)
            m = umin32(m, (uint32_t)__shfl_xor((int)m, s, 64));
        if (lane == 0) idx[(size_t)p*KNB + r] = (int)(m & 0xFFFu);
        bool win = (bk[0] == m);
        #pragma unroll
        for (int t = 0; t < KNB-1; ++t) bk[t] = win ? bk[t+1] : bk[t];
        bk[KNB-1] = win ? 0xFFFFFFFFu : bk[KNB-1];
    }
}

// ---------------- fused pos-MLP + attn-MLP + softmax + aggregate ----------------
__global__ __launch_bounds__(256) void k_attn(
        const float* __restrict__ pos,
        const float* __restrict__ qf, const float* __restrict__ kf, const float* __restrict__ vf,
        const int* __restrict__ idx,
        const float* __restrict__ Wp1, const float* __restrict__ bp1,
        const float* __restrict__ Wp2, const float* __restrict__ bp2,
        const float* __restrict__ Wa1, const float* __restrict__ ba1,
        const float* __restrict__ Wa2, const float* __restrict__ ba2,
        float* __restrict__ agg) {
    __shared__ __align__(16) float qrow[DD];
    __shared__ __align__(16) float ph[KNB][PHH];
    __shared__ __align__(16) float X[KNB][DD];     // x = q - kn + pe;  reused as SIM after phase C
    __shared__ __align__(16) float VPE[KNB][DD];   // v + pe
    __shared__ __align__(16) float T[KNB][AHH];    // relu hidden
    __shared__ int nidx[KNB];

    int p = blockIdx.x;
    int b = p / NN;
    int tid = threadIdx.x;

    if (tid < DD) qrow[tid] = qf[(size_t)p*DD + tid];
    if (tid < KNB) nidx[tid] = idx[(size_t)p*KNB + tid];
    __syncthreads();

    // A1: pos-MLP hidden (20 neighbors x 8)
    if (tid < KNB*PHH) {
        int kk = tid / PHH, jj = tid % PHH;
        int j = nidx[kk];
        const float* pq = pos + (size_t)p*3;
        const float* pn = pos + (size_t)(b*NN + j)*3;
        float r0 = pq[0] - pn[0];
        float r1 = pq[1] - pn[1];
        float r2 = pq[2] - pn[2];
        float a = bp1[jj] + r0*Wp1[jj*3+0] + r1*Wp1[jj*3+1] + r2*Wp1[jj*3+2];
        ph[kk][jj] = fmaxf(a, 0.f);
    }
    __syncthreads();

    // A2: pe, X, VPE  (20*128 elems, 10 iters of 256)
    for (int it = 0; it < (KNB*DD)/256; ++it) {
        int lin = it*256 + tid;
        int kk = lin / DD, d = lin % DD;
        int j = nidx[kk];
        const float* w = Wp2 + (size_t)d*PHH;
        float pe = bp2[d];
        #pragma unroll
        for (int jj = 0; jj < PHH; ++jj) pe += ph[kk][jj] * w[jj];
        float kv = kf[(size_t)(b*NN + j)*DD + d];
        float vv = vf[(size_t)(b*NN + j)*DD + d];
        X[kk][d] = qrow[d] - kv + pe;
        VPE[kk][d] = vv + pe;
    }
    __syncthreads();

    // B: T[kk][a] = relu(X[kk] . Wa1[a] + ba1[a]);  each thread owns rows tid and tid+256
    {
        float acc1[KNB], acc2[KNB];
        #pragma unroll
        for (int i = 0; i < KNB; ++i) { acc1[i] = 0.f; acc2[i] = 0.f; }
        const float* w1 = Wa1 + (size_t)tid*DD;
        const float* w2 = Wa1 + (size_t)(tid+256)*DD;
        for (int d = 0; d < DD; d += 4) {
            float4 u1 = *(const float4*)(w1 + d);
            float4 u2 = *(const float4*)(w2 + d);
            #pragma unroll
            for (int kk = 0; kk < KNB; ++kk) {
                float4 xv = *(const float4*)&X[kk][d];
                acc1[kk] += xv.x*u1.x + xv.y*u1.y + xv.z*u1.z + xv.w*u1.w;
                acc2[kk] += xv.x*u2.x + xv.y*u2.y + xv.z*u2.z + xv.w*u2.w;
            }
        }
        float bb1 = ba1[tid], bb2 = ba1[tid+256];
        #pragma unroll
        for (int kk = 0; kk < KNB; ++kk) {
            T[kk][tid]     = fmaxf(acc1[kk] + bb1, 0.f);
            T[kk][tid+256] = fmaxf(acc2[kk] + bb2, 0.f);
        }
    }
    __syncthreads();

    // C: SIM[kk][d] = T[kk] . Wa2[d] + ba2[d];  thread = (d, kk-half)
    {
        int d = tid & 127, g = tid >> 7;
        float acc[10];
        #pragma unroll
        for (int i = 0; i < 10; ++i) acc[i] = 0.f;
        const float* w = Wa2 + (size_t)d*AHH;
        for (int a = 0; a < AHH; a += 4) {
            float4 u = *(const float4*)(w + a);
            #pragma unroll
            for (int i = 0; i < 10; ++i) {
                float4 tv = *(const float4*)&T[g*10 + i][a];
                acc[i] += tv.x*u.x + tv.y*u.y + tv.z*u.z + tv.w*u.w;
            }
        }
        float bb = ba2[d];
        #pragma unroll
        for (int i = 0; i < 10; ++i) X[g*10 + i][d] = acc[i] + bb;   // X reused as SIM
    }
    __syncthreads();

    // D: softmax over kk per channel + aggregate
    if (tid < DD) {
        int d = tid;
        float m = -3.4e38f;
        #pragma unroll
        for (int kk = 0; kk < KNB; ++kk) m = fmaxf(m, X[kk][d]);
        float e[KNB]; float s = 0.f;
        #pragma unroll
        for (int kk = 0; kk < KNB; ++kk) { e[kk] = __expf(X[kk][d] - m); s += e[kk]; }
        float inv = 1.f / s;
        float a = 0.f;
        #pragma unroll
        for (int kk = 0; kk < KNB; ++kk) a += e[kk]*inv*VPE[kk][d];
        agg[(size_t)p*DD + d] = a;
    }
}

// ---------------- out = h + agg @ W3.T + b3 ----------------
__global__ void k_out(const float* __restrict__ agg, const float* __restrict__ h,
                      const float* __restrict__ W3, const float* __restrict__ b3,
                      float* __restrict__ out) {
    __shared__ __align__(16) float arow[DD];
    int p = blockIdx.x, t = threadIdx.x;
    arow[t] = agg[(size_t)p*DD + t];
    __syncthreads();
    const float* w = W3 + (size_t)t*DD;
    float acc = b3[t];
    for (int d = 0; d < DD; d += 4) {
        float4 w4 = *(const float4*)(w + d);
        acc += arow[d]*w4.x + arow[d+1]*w4.y + arow[d+2]*w4.z + arow[d+3]*w4.w;
    }
    out[(size_t)p*DD + t] = acc + h[(size_t)p*DD + t];
}

extern "C" void kernel_launch(void* const* d_in, const int* in_sizes, int n_in,
                              void* d_out, int out_size, void* d_ws, size_t ws_size,
                              hipStream_t stream) {
    const float* x    = (const float*)d_in[0];
    const float* pos  = (const float*)d_in[1];
    const float* W1   = (const float*)d_in[2];
    const float* b1   = (const float*)d_in[3];
    const float* W2   = (const float*)d_in[4];
    const float* b2   = (const float*)d_in[5];
    const float* W3   = (const float*)d_in[6];
    const float* b3   = (const float*)d_in[7];
    const float* Wqkv = (const float*)d_in[8];
    const float* Wp1  = (const float*)d_in[9];
    const float* bp1  = (const float*)d_in[10];
    const float* Wp2  = (const float*)d_in[11];
    const float* bp2  = (const float*)d_in[12];
    const float* Wa1  = (const float*)d_in[13];
    const float* ba1  = (const float*)d_in[14];
    const float* Wa2  = (const float*)d_in[15];
    const float* ba2  = (const float*)d_in[16];

    float* ws  = (float*)d_ws;
    float* h   = ws;
    float* qf  = ws + 1*(size_t)BN*DD;
    float* kf  = ws + 2*(size_t)BN*DD;
    float* vf  = ws + 3*(size_t)BN*DD;
    float* agg = ws + 4*(size_t)BN*DD;
    int*   idx = (int*)(ws + 5*(size_t)BN*DD);

    k_lin1<<<BN, DD, 0, stream>>>(x, W1, b1, h);
    k_qkv <<<BN, DD, 0, stream>>>(h, W2, b2, Wqkv, qf, kf, vf);
    k_knn <<<BN/4, 256, 0, stream>>>(pos, idx);
    k_attn<<<BN, 256, 0, stream>>>(pos, qf, kf, vf, idx,
                                   Wp1, bp1, Wp2, bp2, Wa1, ba1, Wa2, ba2, agg);
    k_out <<<BN, DD, 0, stream>>>(agg, h, W3, b3, (float*)d_out);
}

// Round 4
// 591.518 us; speedup vs baseline: 11.4330x; 2.3549x over previous
//
#include <hip/hip_runtime.h>
#include <stdint.h>

#define BB 2
#define NN 4096
#define KNB 20
#define DD 128
#define PHH 8
#define AHH 512
#define BN (BB*NN)

typedef unsigned short ushort_t;
typedef short bf16x8 __attribute__((ext_vector_type(8)));
typedef float f32x4 __attribute__((ext_vector_type(4)));

__device__ __forceinline__ uint32_t umin32(uint32_t a, uint32_t b) { return a < b ? a : b; }
__device__ __forceinline__ uint32_t umax32(uint32_t a, uint32_t b) { return a > b ? a : b; }

__device__ __forceinline__ ushort_t f2bf(float f) {   // RNE
    uint32_t x = __float_as_uint(f);
    return (ushort_t)((x + 0x7FFFu + ((x >> 16) & 1u)) >> 16);
}
__device__ __forceinline__ float bf2f(ushort_t u) {
    union { float f; uint32_t i; } c; c.i = ((uint32_t)u) << 16; return c.f;
}
__device__ __forceinline__ uint32_t cvt_pk_bf16(float lo, float hi) {
    uint32_t r;
    asm("v_cvt_pk_bf16_f32 %0, %1, %2" : "=v"(r) : "v"(lo), "v"(hi));
    return r;  // r.lo16 = bf16(lo), r.hi16 = bf16(hi)
}
// load 8 consecutive f32, pack to bf16x8 (B-fragment from row-major weights)
__device__ __forceinline__ bf16x8 load_bfrag(const float* __restrict__ src) {
    float4 x = *(const float4*)src;
    float4 y = *(const float4*)(src + 4);
    union { bf16x8 v; uint32_t u[4]; } r;
    r.u[0] = cvt_pk_bf16(x.x, x.y);
    r.u[1] = cvt_pk_bf16(x.z, x.w);
    r.u[2] = cvt_pk_bf16(y.x, y.y);
    r.u[3] = cvt_pk_bf16(y.z, y.w);
    return r.v;
}

// XOR swizzle for [m][*] bf16 tiles with 256-B row stride (T2: break 32-way conflicts)
#define SW(m, byteInRow) ((m)*256 + ((byteInRow) ^ (((m)&7) << 4)))

// ---------------- linear1: h = x @ W1.T + b1 ----------------
__global__ void k_lin1(const float* __restrict__ x, const float* __restrict__ W1,
                       const float* __restrict__ b1, float* __restrict__ h) {
    int p = blockIdx.x;
    int t = threadIdx.x;
    float x0 = x[p*3+0], x1 = x[p*3+1], x2 = x[p*3+2];
    float acc = b1[t] + x0*W1[t*3+0] + x1*W1[t*3+1] + x2*W1[t*3+2];
    h[(size_t)p*DD + t] = acc;
}

// ---------------- linear2 + qkv ----------------
__global__ void k_qkv(const float* __restrict__ h, const float* __restrict__ W2,
                      const float* __restrict__ b2, const float* __restrict__ Wqkv,
                      float* __restrict__ qf, float* __restrict__ kf, float* __restrict__ vf) {
    __shared__ __align__(16) float hrow[DD];
    __shared__ __align__(16) float h1row[DD];
    int p = blockIdx.x, t = threadIdx.x;
    hrow[t] = h[(size_t)p*DD + t];
    __syncthreads();
    float acc = b2[t];
    const float* w = W2 + (size_t)t*DD;
    for (int d = 0; d < DD; d += 4) {
        float4 w4 = *(const float4*)(w + d);
        acc += hrow[d]*w4.x + hrow[d+1]*w4.y + hrow[d+2]*w4.z + hrow[d+3]*w4.w;
    }
    h1row[t] = acc;
    __syncthreads();
    for (int r = 0; r < 3; ++r) {
        const float* wr = Wqkv + (size_t)(r*DD + t)*DD;
        float a2 = 0.f;
        for (int d = 0; d < DD; d += 4) {
            float4 w4 = *(const float4*)(wr + d);
            a2 += h1row[d]*w4.x + h1row[d+1]*w4.y + h1row[d+2]*w4.z + h1row[d+3]*w4.w;
        }
        float* dst = (r == 0) ? qf : (r == 1) ? kf : vf;
        dst[(size_t)p*DD + t] = a2;
    }
}

// ---------------- KNN: one wave per query, register top-20 via packed keys ----------------
__global__ __launch_bounds__(256) void k_knn(const float* __restrict__ pos, int* __restrict__ idx) {
    int wid  = threadIdx.x >> 6;
    int lane = threadIdx.x & 63;
    int p = blockIdx.x*4 + wid;
    int b = p >> 12;
    float qx = pos[p*3+0], qy = pos[p*3+1], qz = pos[p*3+2];
    const float* pb = pos + (size_t)b*NN*3;

    uint32_t bk[KNB];
    #pragma unroll
    for (int i = 0; i < KNB; ++i) bk[i] = 0xFFFFFFFFu;

    for (int i = 0; i < NN/64; ++i) {
        int j = i*64 + lane;
        float dx = qx - pb[j*3+0];
        float dy = qy - pb[j*3+1];
        float dz = qz - pb[j*3+2];
        float d2 = dx*dx + dy*dy + dz*dz;
        uint32_t key = (__float_as_uint(d2) & 0xFFFFF000u) | (uint32_t)j;
        if (key < bk[KNB-1]) {
            uint32_t c = key;
            #pragma unroll
            for (int t = 0; t < KNB; ++t) {
                uint32_t lo = umin32(c, bk[t]);
                uint32_t hi = umax32(c, bk[t]);
                bk[t] = lo; c = hi;
            }
        }
    }
    for (int r = 0; r < KNB; ++r) {
        uint32_t m = bk[0];
        #pragma unroll
        for (int s = 1; s < 64; s <<= 1)
            m = umin32(m, (uint32_t)__shfl_xor((int)m, s, 64));
        if (lane == 0) idx[(size_t)p*KNB + r] = (int)(m & 0xFFFu);
        bool win = (bk[0] == m);
        #pragma unroll
        for (int t = 0; t < KNB-1; ++t) bk[t] = win ? bk[t+1] : bk[t];
        bk[KNB-1] = win ? 0xFFFFFFFFu : bk[KNB-1];
    }
}

// ---------------- fused pos-MLP + MFMA attn-MLP + softmax + aggregate ----------------
// 4 query points per block (M = 80 = 5 row-tiles), 4 waves, hidden dim in 4 chunks of 128.
// LDS: Xl[80][128]bf16(swz) @0, Tl[80][128]bf16(swz) @20480, SIMl[80][128]f32 @0 (union),
//      VPEl[80][128]bf16 @40960, ph[80][8]f32 @61440, nidx[80] @64000. Total 64320 B.
#define XL_OFF 0
#define TL_OFF 20480
#define VPE_OFF 40960
#define PH_OFF 61440
#define NIDX_OFF 64000

__global__ __launch_bounds__(256) void k_attn(
        const float* __restrict__ pos,
        const float* __restrict__ qf, const float* __restrict__ kf, const float* __restrict__ vf,
        const int* __restrict__ idx,
        const float* __restrict__ Wp1, const float* __restrict__ bp1,
        const float* __restrict__ Wp2, const float* __restrict__ bp2,
        const float* __restrict__ Wa1, const float* __restrict__ ba1,
        const float* __restrict__ Wa2, const float* __restrict__ ba2,
        float* __restrict__ agg) {
    __shared__ __align__(16) char smem[64320];
    float* phv  = (float*)(smem + PH_OFF);
    int*   nidx = (int*)(smem + NIDX_OFF);

    int tid  = threadIdx.x;
    int w    = tid >> 6;
    int lane = tid & 63;
    int p0   = blockIdx.x * 4;      // 4 points per block; 4096%4==0 so b uniform per block
    int b    = p0 >> 12;

    if (tid < 80) nidx[tid] = idx[(size_t)(p0 + tid/20)*KNB + (tid%20)];
    __syncthreads();

    // A1: pos-MLP hidden: ph[m][jj], m = g*20+kk
    for (int lin = tid; lin < 80*PHH; lin += 256) {
        int m = lin >> 3, jj = lin & 7;
        int g = m / 20;
        int j = nidx[m];
        const float* pq = pos + (size_t)(p0 + g)*3;
        const float* pn = pos + (size_t)(b*NN + j)*3;
        float r0 = pq[0]-pn[0], r1 = pq[1]-pn[1], r2 = pq[2]-pn[2];
        float a = bp1[jj] + r0*Wp1[jj*3+0] + r1*Wp1[jj*3+1] + r2*Wp1[jj*3+2];
        phv[m*PHH + jj] = fmaxf(a, 0.f);
    }
    __syncthreads();

    // A2: pe, X (bf16, swizzled), VPE (bf16)
    for (int lin = tid; lin < 80*DD; lin += 256) {
        int m = lin >> 7, d = lin & 127;
        int g = m / 20;
        int j = nidx[m];
        const float* wp = Wp2 + (size_t)d*PHH;
        float pe = bp2[d];
        #pragma unroll
        for (int jj = 0; jj < PHH; ++jj) pe += phv[m*PHH + jj] * wp[jj];
        float qv = qf[(size_t)(p0 + g)*DD + d];
        float kv = kf[(size_t)(b*NN + j)*DD + d];
        float vv = vf[(size_t)(b*NN + j)*DD + d];
        *(ushort_t*)&smem[XL_OFF + SW(m, d*2)] = f2bf(qv - kv + pe);
        *(ushort_t*)&smem[VPE_OFF + m*256 + d*2] = f2bf(vv + pe);
    }
    __syncthreads();

    // chunked attn-MLP: SIM[80][128] accumulated over 4 chunks of hidden dim
    f32x4 accS[5][2];
    #pragma unroll
    for (int mt = 0; mt < 5; ++mt)
        #pragma unroll
        for (int ntl = 0; ntl < 2; ++ntl)
            accS[mt][ntl] = (f32x4){0.f, 0.f, 0.f, 0.f};

    for (int c = 0; c < 4; ++c) {
        // B: T_chunk = relu(X @ Wa1_c^T + ba1_c)   [80][128]
        f32x4 accB[5][2];
        #pragma unroll
        for (int mt = 0; mt < 5; ++mt)
            #pragma unroll
            for (int ntl = 0; ntl < 2; ++ntl)
                accB[mt][ntl] = (f32x4){0.f, 0.f, 0.f, 0.f};

        #pragma unroll
        for (int ks = 0; ks < 4; ++ks) {
            int k0 = ks*32 + (lane >> 4)*8;
            bf16x8 aF[5];
            #pragma unroll
            for (int mt = 0; mt < 5; ++mt) {
                int m = mt*16 + (lane & 15);
                aF[mt] = *(const bf16x8*)&smem[XL_OFF + SW(m, k0*2)];
            }
            #pragma unroll
            for (int ntl = 0; ntl < 2; ++ntl) {
                int acol = c*128 + (2*w + ntl)*16 + (lane & 15);
                bf16x8 bF = load_bfrag(Wa1 + (size_t)acol*DD + k0);
                #pragma unroll
                for (int mt = 0; mt < 5; ++mt)
                    accB[mt][ntl] = __builtin_amdgcn_mfma_f32_16x16x32_bf16(aF[mt], bF, accB[mt][ntl], 0, 0, 0);
            }
        }
        #pragma unroll
        for (int ntl = 0; ntl < 2; ++ntl) {
            int al = (2*w + ntl)*16 + (lane & 15);      // local col in chunk
            float bias = ba1[c*128 + al];
            #pragma unroll
            for (int mt = 0; mt < 5; ++mt)
                #pragma unroll
                for (int i = 0; i < 4; ++i) {
                    int m = mt*16 + (lane >> 4)*4 + i;
                    float t = fmaxf(accB[mt][ntl][i] + bias, 0.f);
                    *(ushort_t*)&smem[TL_OFF + SW(m, al*2)] = f2bf(t);
                }
        }
        __syncthreads();

        // C: SIM += T_chunk @ Wa2_c^T
        #pragma unroll
        for (int ks = 0; ks < 4; ++ks) {
            int k0 = ks*32 + (lane >> 4)*8;
            bf16x8 aF[5];
            #pragma unroll
            for (int mt = 0; mt < 5; ++mt) {
                int m = mt*16 + (lane & 15);
                aF[mt] = *(const bf16x8*)&smem[TL_OFF + SW(m, k0*2)];
            }
            #pragma unroll
            for (int ntl = 0; ntl < 2; ++ntl) {
                int d = (2*w + ntl)*16 + (lane & 15);
                bf16x8 bF = load_bfrag(Wa2 + (size_t)d*AHH + c*128 + k0);
                #pragma unroll
                for (int mt = 0; mt < 5; ++mt)
                    accS[mt][ntl] = __builtin_amdgcn_mfma_f32_16x16x32_bf16(aF[mt], bF, accS[mt][ntl], 0, 0, 0);
            }
        }
        __syncthreads();   // Tl readers done before next chunk overwrites
    }

    // SIM -> LDS f32 (overlaps dead Xl+Tl)
    #pragma unroll
    for (int ntl = 0; ntl < 2; ++ntl) {
        int d = (2*w + ntl)*16 + (lane & 15);
        float bias2 = ba2[d];
        #pragma unroll
        for (int mt = 0; mt < 5; ++mt)
            #pragma unroll
            for (int i = 0; i < 4; ++i) {
                int m = mt*16 + (lane >> 4)*4 + i;
                *(float*)&smem[(m*DD + d)*4] = accS[mt][ntl][i] + bias2;
            }
    }
    __syncthreads();

    // D: softmax over kk + aggregate
    for (int it = 0; it < 2; ++it) {
        int lin = it*256 + tid;          // 0..511 = (g, d)
        int g = lin >> 7, d = lin & 127;
        const float* simc = (const float*)&smem[(g*20*DD + d)*4];
        float mx = -3.4e38f;
        #pragma unroll
        for (int kk = 0; kk < KNB; ++kk) mx = fmaxf(mx, simc[kk*DD]);
        float e[KNB]; float s = 0.f;
        #pragma unroll
        for (int kk = 0; kk < KNB; ++kk) { e[kk] = __expf(simc[kk*DD] - mx); s += e[kk]; }
        float inv = 1.f / s;
        float a = 0.f;
        #pragma unroll
        for (int kk = 0; kk < KNB; ++kk)
            a += e[kk] * bf2f(*(const ushort_t*)&smem[VPE_OFF + (g*20 + kk)*256 + d*2]);
        agg[(size_t)(p0 + g)*DD + d] = a * inv;
    }
}

// ---------------- out = h + agg @ W3.T + b3 ----------------
__global__ void k_out(const float* __restrict__ agg, const float* __restrict__ h,
                      const float* __restrict__ W3, const float* __restrict__ b3,
                      float* __restrict__ out) {
    __shared__ __align__(16) float arow[DD];
    int p = blockIdx.x, t = threadIdx.x;
    arow[t] = agg[(size_t)p*DD + t];
    __syncthreads();
    const float* w = W3 + (size_t)t*DD;
    float acc = b3[t];
    for (int d = 0; d < DD; d += 4) {
        float4 w4 = *(const float4*)(w + d);
        acc += arow[d]*w4.x + arow[d+1]*w4.y + arow[d+2]*w4.z + arow[d+3]*w4.w;
    }
    out[(size_t)p*DD + t] = acc + h[(size_t)p*DD + t];
}

extern "C" void kernel_launch(void* const* d_in, const int* in_sizes, int n_in,
                              void* d_out, int out_size, void* d_ws, size_t ws_size,
                              hipStream_t stream) {
    const float* x    = (const float*)d_in[0];
    const float* pos  = (const float*)d_in[1];
    const float* W1   = (const float*)d_in[2];
    const float* b1   = (const float*)d_in[3];
    const float* W2   = (const float*)d_in[4];
    const float* b2   = (const float*)d_in[5];
    const float* W3   = (const float*)d_in[6];
    const float* b3   = (const float*)d_in[7];
    const float* Wqkv = (const float*)d_in[8];
    const float* Wp1  = (const float*)d_in[9];
    const float* bp1  = (const float*)d_in[10];
    const float* Wp2  = (const float*)d_in[11];
    const float* bp2  = (const float*)d_in[12];
    const float* Wa1  = (const float*)d_in[13];
    const float* ba1  = (const float*)d_in[14];
    const float* Wa2  = (const float*)d_in[15];
    const float* ba2  = (const float*)d_in[16];

    float* ws  = (float*)d_ws;
    float* h   = ws;
    float* qf  = ws + 1*(size_t)BN*DD;
    float* kf  = ws + 2*(size_t)BN*DD;
    float* vf  = ws + 3*(size_t)BN*DD;
    float* agg = ws + 4*(size_t)BN*DD;
    int*   idx = (int*)(ws + 5*(size_t)BN*DD);

    k_lin1<<<BN, DD, 0, stream>>>(x, W1, b1, h);
    k_qkv <<<BN, DD, 0, stream>>>(h, W2, b2, Wqkv, qf, kf, vf);
    k_knn <<<BN/4, 256, 0, stream>>>(pos, idx);
    k_attn<<<BN/4, 256, 0, stream>>>(pos, qf, kf, vf, idx,
                                     Wp1, bp1, Wp2, bp2, Wa1, ba1, Wa2, ba2, agg);
    k_out <<<BN, DD, 0, stream>>>(agg, h, W3, b3, (float*)d_out);
}

// Round 5
// 273.311 us; speedup vs baseline: 24.7442x; 2.1643x over previous
//
#include <hip/hip_runtime.h>
#include <stdint.h>

#define BB 2
#define NN 4096
#define KNB 20
#define DD 128
#define PHH 8
#define AHH 512
#define BN (BB*NN)

typedef unsigned short ushort_t;
typedef short bf16x8 __attribute__((ext_vector_type(8)));
typedef float f32x4 __attribute__((ext_vector_type(4)));

__device__ __forceinline__ uint32_t umin32(uint32_t a, uint32_t b) { return a < b ? a : b; }
__device__ __forceinline__ uint32_t umax32(uint32_t a, uint32_t b) { return a > b ? a : b; }

__device__ __forceinline__ ushort_t f2bf(float f) {   // RNE
    uint32_t x = __float_as_uint(f);
    return (ushort_t)((x + 0x7FFFu + ((x >> 16) & 1u)) >> 16);
}
__device__ __forceinline__ float bf2f(ushort_t u) {
    union { float f; uint32_t i; } c; c.i = ((uint32_t)u) << 16; return c.f;
}
__device__ __forceinline__ uint32_t cvt_pk_bf16(float lo, float hi) {
    uint32_t r;
    asm("v_cvt_pk_bf16_f32 %0, %1, %2" : "=v"(r) : "v"(lo), "v"(hi));
    return r;
}
// load 8 consecutive f32, pack to bf16x8 (B-fragment from row-major weights, L2-hot)
__device__ __forceinline__ bf16x8 load_bfrag(const float* __restrict__ src) {
    float4 x = *(const float4*)src;
    float4 y = *(const float4*)(src + 4);
    union { bf16x8 v; uint32_t u[4]; } r;
    r.u[0] = cvt_pk_bf16(x.x, x.y);
    r.u[1] = cvt_pk_bf16(x.z, x.w);
    r.u[2] = cvt_pk_bf16(y.x, y.y);
    r.u[3] = cvt_pk_bf16(y.z, y.w);
    return r.v;
}

// XOR swizzle for [m][*] bf16 tiles with 256-B row stride (T2: break 32-way conflicts)
#define SW(m, byteInRow) ((m)*256 + ((byteInRow) ^ (((m)&7) << 4)))

// ---------------- fused linear1 + linear2 + to_qkv (MFMA) ----------------
// 32 points/block, 256 blocks, 4 waves. LDS: HL bf16[32][128]swz @0,
// H1L bf16[32][128]swz @8192, xs f32[96] @16384.
__global__ __launch_bounds__(256) void k_front(
        const float* __restrict__ x,
        const float* __restrict__ W1, const float* __restrict__ b1,
        const float* __restrict__ W2, const float* __restrict__ b2,
        const float* __restrict__ Wqkv,
        float* __restrict__ h, float* __restrict__ qf,
        float* __restrict__ kf, float* __restrict__ vf) {
    __shared__ __align__(16) char smem[16384 + 512];
    float* xs = (float*)(smem + 16384);
    int tid = threadIdx.x, w = tid >> 6, lane = tid & 63;
    int p0 = blockIdx.x * 32;

    if (tid < 96) xs[tid] = x[(size_t)p0*3 + tid];
    __syncthreads();

    // A: h = x@W1^T + b1  (f32 to global for residual; bf16 swizzled to LDS)
    #pragma unroll
    for (int it = 0; it < 16; ++it) {
        int lin = it*256 + tid;
        int m = lin >> 7, d = lin & 127;
        float hv = b1[d] + xs[m*3+0]*W1[d*3+0] + xs[m*3+1]*W1[d*3+1] + xs[m*3+2]*W1[d*3+2];
        h[(size_t)(p0+m)*DD + d] = hv;
        *(ushort_t*)&smem[SW(m, d*2)] = f2bf(hv);
    }
    __syncthreads();

    // B: h1 = h@W2^T + b2 -> H1L (bf16 swizzled)
    {
        f32x4 acc[2][2];
        #pragma unroll
        for (int mt = 0; mt < 2; ++mt)
            #pragma unroll
            for (int ntl = 0; ntl < 2; ++ntl) acc[mt][ntl] = (f32x4){0,0,0,0};
        #pragma unroll
        for (int ks = 0; ks < 4; ++ks) {
            int k0 = ks*32 + (lane >> 4)*8;
            bf16x8 aF[2];
            #pragma unroll
            for (int mt = 0; mt < 2; ++mt)
                aF[mt] = *(const bf16x8*)&smem[SW(mt*16 + (lane & 15), k0*2)];
            #pragma unroll
            for (int ntl = 0; ntl < 2; ++ntl) {
                int n = (2*w + ntl)*16 + (lane & 15);
                bf16x8 bF = load_bfrag(W2 + (size_t)n*DD + k0);
                #pragma unroll
                for (int mt = 0; mt < 2; ++mt)
                    acc[mt][ntl] = __builtin_amdgcn_mfma_f32_16x16x32_bf16(aF[mt], bF, acc[mt][ntl], 0, 0, 0);
            }
        }
        #pragma unroll
        for (int ntl = 0; ntl < 2; ++ntl) {
            int n = (2*w + ntl)*16 + (lane & 15);
            float bias = b2[n];
            #pragma unroll
            for (int mt = 0; mt < 2; ++mt)
                #pragma unroll
                for (int i = 0; i < 4; ++i) {
                    int m = mt*16 + (lane >> 4)*4 + i;
                    *(ushort_t*)&smem[8192 + SW(m, n*2)] = f2bf(acc[mt][ntl][i] + bias);
                }
        }
    }
    __syncthreads();

    // C: qkv = h1@Wqkv^T  (N=384: wave w owns n-tiles w*6..w*6+5)
    {
        f32x4 acc[2][6];
        #pragma unroll
        for (int mt = 0; mt < 2; ++mt)
            #pragma unroll
            for (int ntl = 0; ntl < 6; ++ntl) acc[mt][ntl] = (f32x4){0,0,0,0};
        #pragma unroll
        for (int ks = 0; ks < 4; ++ks) {
            int k0 = ks*32 + (lane >> 4)*8;
            bf16x8 aF[2];
            #pragma unroll
            for (int mt = 0; mt < 2; ++mt)
                aF[mt] = *(const bf16x8*)&smem[8192 + SW(mt*16 + (lane & 15), k0*2)];
            #pragma unroll
            for (int ntl = 0; ntl < 6; ++ntl) {
                int n = (w*6 + ntl)*16 + (lane & 15);
                bf16x8 bF = load_bfrag(Wqkv + (size_t)n*DD + k0);
                #pragma unroll
                for (int mt = 0; mt < 2; ++mt)
                    acc[mt][ntl] = __builtin_amdgcn_mfma_f32_16x16x32_bf16(aF[mt], bF, acc[mt][ntl], 0, 0, 0);
            }
        }
        #pragma unroll
        for (int ntl = 0; ntl < 6; ++ntl) {
            int n = (w*6 + ntl)*16 + (lane & 15);
            int r = n >> 7, d = n & 127;       // uniform per (w,ntl): 16-col tiles don't cross 128
            float* dst = (r == 0) ? qf : (r == 1) ? kf : vf;
            #pragma unroll
            for (int mt = 0; mt < 2; ++mt)
                #pragma unroll
                for (int i = 0; i < 4; ++i) {
                    int m = mt*16 + (lane >> 4)*4 + i;
                    dst[(size_t)(p0+m)*DD + d] = acc[mt][ntl][i];
                }
        }
    }
}

// ---------------- KNN: one wave per query, register top-20 via packed keys ----------------
__global__ __launch_bounds__(256) void k_knn(const float* __restrict__ pos, int* __restrict__ idx) {
    int wid  = threadIdx.x >> 6;
    int lane = threadIdx.x & 63;
    int p = blockIdx.x*4 + wid;
    int b = p >> 12;
    float qx = pos[p*3+0], qy = pos[p*3+1], qz = pos[p*3+2];
    const float* pb = pos + (size_t)b*NN*3;

    uint32_t bk[KNB];
    #pragma unroll
    for (int i = 0; i < KNB; ++i) bk[i] = 0xFFFFFFFFu;

    for (int i = 0; i < NN/64; ++i) {
        int j = i*64 + lane;
        float dx = qx - pb[j*3+0];
        float dy = qy - pb[j*3+1];
        float dz = qz - pb[j*3+2];
        float d2 = dx*dx + dy*dy + dz*dz;
        uint32_t key = (__float_as_uint(d2) & 0xFFFFF000u) | (uint32_t)j;
        if (key < bk[KNB-1]) {
            uint32_t c = key;
            #pragma unroll
            for (int t = 0; t < KNB; ++t) {
                uint32_t lo = umin32(c, bk[t]);
                uint32_t hi = umax32(c, bk[t]);
                bk[t] = lo; c = hi;
            }
        }
    }
    for (int r = 0; r < KNB; ++r) {
        uint32_t m = bk[0];
        #pragma unroll
        for (int s = 1; s < 64; s <<= 1)
            m = umin32(m, (uint32_t)__shfl_xor((int)m, s, 64));
        if (lane == 0) idx[(size_t)p*KNB + r] = (int)(m & 0xFFFu);
        bool win = (bk[0] == m);
        #pragma unroll
        for (int t = 0; t < KNB-1; ++t) bk[t] = win ? bk[t+1] : bk[t];
        bk[KNB-1] = win ? 0xFFFFFFFFu : bk[KNB-1];
    }
}

// ---------------- fused pos-MLP + MFMA attn-MLP + softmax + aggregate ----------------
#define XL_OFF 0
#define TL_OFF 20480
#define VPE_OFF 40960
#define PH_OFF 61440
#define NIDX_OFF 64000

__global__ __launch_bounds__(256) void k_attn(
        const float* __restrict__ pos,
        const float* __restrict__ qf, const float* __restrict__ kf, const float* __restrict__ vf,
        const int* __restrict__ idx,
        const float* __restrict__ Wp1, const float* __restrict__ bp1,
        const float* __restrict__ Wp2, const float* __restrict__ bp2,
        const float* __restrict__ Wa1, const float* __restrict__ ba1,
        const float* __restrict__ Wa2, const float* __restrict__ ba2,
        float* __restrict__ agg) {
    __shared__ __align__(16) char smem[64320];
    float* phv  = (float*)(smem + PH_OFF);
    int*   nidx = (int*)(smem + NIDX_OFF);

    int tid  = threadIdx.x;
    int w    = tid >> 6;
    int lane = tid & 63;
    int p0   = blockIdx.x * 4;
    int b    = p0 >> 12;

    if (tid < 80) nidx[tid] = idx[(size_t)(p0 + tid/20)*KNB + (tid%20)];
    __syncthreads();

    for (int lin = tid; lin < 80*PHH; lin += 256) {
        int m = lin >> 3, jj = lin & 7;
        int g = m / 20;
        int j = nidx[m];
        const float* pq = pos + (size_t)(p0 + g)*3;
        const float* pn = pos + (size_t)(b*NN + j)*3;
        float r0 = pq[0]-pn[0], r1 = pq[1]-pn[1], r2 = pq[2]-pn[2];
        float a = bp1[jj] + r0*Wp1[jj*3+0] + r1*Wp1[jj*3+1] + r2*Wp1[jj*3+2];
        phv[m*PHH + jj] = fmaxf(a, 0.f);
    }
    __syncthreads();

    for (int lin = tid; lin < 80*DD; lin += 256) {
        int m = lin >> 7, d = lin & 127;
        int g = m / 20;
        int j = nidx[m];
        const float* wp = Wp2 + (size_t)d*PHH;
        float pe = bp2[d];
        #pragma unroll
        for (int jj = 0; jj < PHH; ++jj) pe += phv[m*PHH + jj] * wp[jj];
        float qv = qf[(size_t)(p0 + g)*DD + d];
        float kv = kf[(size_t)(b*NN + j)*DD + d];
        float vv = vf[(size_t)(b*NN + j)*DD + d];
        *(ushort_t*)&smem[XL_OFF + SW(m, d*2)] = f2bf(qv - kv + pe);
        *(ushort_t*)&smem[VPE_OFF + m*256 + d*2] = f2bf(vv + pe);
    }
    __syncthreads();

    f32x4 accS[5][2];
    #pragma unroll
    for (int mt = 0; mt < 5; ++mt)
        #pragma unroll
        for (int ntl = 0; ntl < 2; ++ntl)
            accS[mt][ntl] = (f32x4){0.f, 0.f, 0.f, 0.f};

    for (int c = 0; c < 4; ++c) {
        f32x4 accB[5][2];
        #pragma unroll
        for (int mt = 0; mt < 5; ++mt)
            #pragma unroll
            for (int ntl = 0; ntl < 2; ++ntl)
                accB[mt][ntl] = (f32x4){0.f, 0.f, 0.f, 0.f};

        #pragma unroll
        for (int ks = 0; ks < 4; ++ks) {
            int k0 = ks*32 + (lane >> 4)*8;
            bf16x8 aF[5];
            #pragma unroll
            for (int mt = 0; mt < 5; ++mt) {
                int m = mt*16 + (lane & 15);
                aF[mt] = *(const bf16x8*)&smem[XL_OFF + SW(m, k0*2)];
            }
            #pragma unroll
            for (int ntl = 0; ntl < 2; ++ntl) {
                int acol = c*128 + (2*w + ntl)*16 + (lane & 15);
                bf16x8 bF = load_bfrag(Wa1 + (size_t)acol*DD + k0);
                #pragma unroll
                for (int mt = 0; mt < 5; ++mt)
                    accB[mt][ntl] = __builtin_amdgcn_mfma_f32_16x16x32_bf16(aF[mt], bF, accB[mt][ntl], 0, 0, 0);
            }
        }
        #pragma unroll
        for (int ntl = 0; ntl < 2; ++ntl) {
            int al = (2*w + ntl)*16 + (lane & 15);
            float bias = ba1[c*128 + al];
            #pragma unroll
            for (int mt = 0; mt < 5; ++mt)
                #pragma unroll
                for (int i = 0; i < 4; ++i) {
                    int m = mt*16 + (lane >> 4)*4 + i;
                    float t = fmaxf(accB[mt][ntl][i] + bias, 0.f);
                    *(ushort_t*)&smem[TL_OFF + SW(m, al*2)] = f2bf(t);
                }
        }
        __syncthreads();

        #pragma unroll
        for (int ks = 0; ks < 4; ++ks) {
            int k0 = ks*32 + (lane >> 4)*8;
            bf16x8 aF[5];
            #pragma unroll
            for (int mt = 0; mt < 5; ++mt) {
                int m = mt*16 + (lane & 15);
                aF[mt] = *(const bf16x8*)&smem[TL_OFF + SW(m, k0*2)];
            }
            #pragma unroll
            for (int ntl = 0; ntl < 2; ++ntl) {
                int d = (2*w + ntl)*16 + (lane & 15);
                bf16x8 bF = load_bfrag(Wa2 + (size_t)d*AHH + c*128 + k0);
                #pragma unroll
                for (int mt = 0; mt < 5; ++mt)
                    accS[mt][ntl] = __builtin_amdgcn_mfma_f32_16x16x32_bf16(aF[mt], bF, accS[mt][ntl], 0, 0, 0);
            }
        }
        __syncthreads();
    }

    #pragma unroll
    for (int ntl = 0; ntl < 2; ++ntl) {
        int d = (2*w + ntl)*16 + (lane & 15);
        float bias2 = ba2[d];
        #pragma unroll
        for (int mt = 0; mt < 5; ++mt)
            #pragma unroll
            for (int i = 0; i < 4; ++i) {
                int m = mt*16 + (lane >> 4)*4 + i;
                *(float*)&smem[(m*DD + d)*4] = accS[mt][ntl][i] + bias2;
            }
    }
    __syncthreads();

    for (int it = 0; it < 2; ++it) {
        int lin = it*256 + tid;
        int g = lin >> 7, d = lin & 127;
        const float* simc = (const float*)&smem[(g*20*DD + d)*4];
        float mx = -3.4e38f;
        #pragma unroll
        for (int kk = 0; kk < KNB; ++kk) mx = fmaxf(mx, simc[kk*DD]);
        float e[KNB]; float s = 0.f;
        #pragma unroll
        for (int kk = 0; kk < KNB; ++kk) { e[kk] = __expf(simc[kk*DD] - mx); s += e[kk]; }
        float inv = 1.f / s;
        float a = 0.f;
        #pragma unroll
        for (int kk = 0; kk < KNB; ++kk)
            a += e[kk] * bf2f(*(const ushort_t*)&smem[VPE_OFF + (g*20 + kk)*256 + d*2]);
        agg[(size_t)(p0 + g)*DD + d] = a * inv;
    }
}

// ---------------- out = h + agg @ W3.T + b3 (MFMA, 32 pts/block) ----------------
__global__ __launch_bounds__(256) void k_out(
        const float* __restrict__ agg, const float* __restrict__ h,
        const float* __restrict__ W3, const float* __restrict__ b3,
        float* __restrict__ out) {
    __shared__ __align__(16) char smem[8192];
    int tid = threadIdx.x, w = tid >> 6, lane = tid & 63;
    int p0 = blockIdx.x * 32;

    #pragma unroll
    for (int it = 0; it < 16; ++it) {
        int lin = it*256 + tid;
        int m = lin >> 7, d = lin & 127;
        *(ushort_t*)&smem[SW(m, d*2)] = f2bf(agg[(size_t)(p0+m)*DD + d]);
    }
    __syncthreads();

    f32x4 acc[2][2];
    #pragma unroll
    for (int mt = 0; mt < 2; ++mt)
        #pragma unroll
        for (int ntl = 0; ntl < 2; ++ntl) acc[mt][ntl] = (f32x4){0,0,0,0};
    #pragma unroll
    for (int ks = 0; ks < 4; ++ks) {
        int k0 = ks*32 + (lane >> 4)*8;
        bf16x8 aF[2];
        #pragma unroll
        for (int mt = 0; mt < 2; ++mt)
            aF[mt] = *(const bf16x8*)&smem[SW(mt*16 + (lane & 15), k0*2)];
        #pragma unroll
        for (int ntl = 0; ntl < 2; ++ntl) {
            int n = (2*w + ntl)*16 + (lane & 15);
            bf16x8 bF = load_bfrag(W3 + (size_t)n*DD + k0);
            #pragma unroll
            for (int mt = 0; mt < 2; ++mt)
                acc[mt][ntl] = __builtin_amdgcn_mfma_f32_16x16x32_bf16(aF[mt], bF, acc[mt][ntl], 0, 0, 0);
        }
    }
    #pragma unroll
    for (int ntl = 0; ntl < 2; ++ntl) {
        int n = (2*w + ntl)*16 + (lane & 15);
        float bias = b3[n];
        #pragma unroll
        for (int mt = 0; mt < 2; ++mt)
            #pragma unroll
            for (int i = 0; i < 4; ++i) {
                int m = mt*16 + (lane >> 4)*4 + i;
                size_t o = (size_t)(p0+m)*DD + n;
                out[o] = acc[mt][ntl][i] + bias + h[o];
            }
    }
}

extern "C" void kernel_launch(void* const* d_in, const int* in_sizes, int n_in,
                              void* d_out, int out_size, void* d_ws, size_t ws_size,
                              hipStream_t stream) {
    const float* x    = (const float*)d_in[0];
    const float* pos  = (const float*)d_in[1];
    const float* W1   = (const float*)d_in[2];
    const float* b1   = (const float*)d_in[3];
    const float* W2   = (const float*)d_in[4];
    const float* b2   = (const float*)d_in[5];
    const float* W3   = (const float*)d_in[6];
    const float* b3   = (const float*)d_in[7];
    const float* Wqkv = (const float*)d_in[8];
    const float* Wp1  = (const float*)d_in[9];
    const float* bp1  = (const float*)d_in[10];
    const float* Wp2  = (const float*)d_in[11];
    const float* bp2  = (const float*)d_in[12];
    const float* Wa1  = (const float*)d_in[13];
    const float* ba1  = (const float*)d_in[14];
    const float* Wa2  = (const float*)d_in[15];
    const float* ba2  = (const float*)d_in[16];

    float* ws  = (float*)d_ws;
    float* h   = ws;
    float* qf  = ws + 1*(size_t)BN*DD;
    float* kf  = ws + 2*(size_t)BN*DD;
    float* vf  = ws + 3*(size_t)BN*DD;
    float* agg = ws + 4*(size_t)BN*DD;
    int*   idx = (int*)(ws + 5*(size_t)BN*DD);

    k_front<<<BN/32, 256, 0, stream>>>(x, W1, b1, W2, b2, Wqkv, h, qf, kf, vf);
    k_knn  <<<BN/4, 256, 0, stream>>>(pos, idx);
    k_attn <<<BN/4, 256, 0, stream>>>(pos, qf, kf, vf, idx,
                                      Wp1, bp1, Wp2, bp2, Wa1, ba1, Wa2, ba2, agg);
    k_out  <<<BN/32, 256, 0, stream>>>(agg, h, W3, b3, (float*)d_out);
}

// Round 6
// 179.864 us; speedup vs baseline: 37.5998x; 1.5195x over previous
//
#include <hip/hip_runtime.h>
#include <stdint.h>

#define BB 2
#define NN 4096
#define KNB 20
#define DD 128
#define PHH 8
#define AHH 512
#define BN (BB*NN)

typedef unsigned short ushort_t;
typedef short bf16x8 __attribute__((ext_vector_type(8)));
typedef float f32x4 __attribute__((ext_vector_type(4)));

__device__ __forceinline__ uint32_t umin32(uint32_t a, uint32_t b) { return a < b ? a : b; }
__device__ __forceinline__ uint32_t umax32(uint32_t a, uint32_t b) { return a > b ? a : b; }

__device__ __forceinline__ ushort_t f2bf(float f) {   // RNE
    uint32_t x = __float_as_uint(f);
    return (ushort_t)((x + 0x7FFFu + ((x >> 16) & 1u)) >> 16);
}
__device__ __forceinline__ float bf2f(ushort_t u) {
    union { float f; uint32_t i; } c; c.i = ((uint32_t)u) << 16; return c.f;
}

// XOR swizzles: row-major bf16 tiles, stride 256 B / 128 B
#define SW256(m, byteInRow) ((m)*256 + ((byteInRow) ^ (((m)&7) << 4)))
#define SW128(m, byteInRow) ((m)*128 + ((byteInRow) ^ (((m)&7) << 4)))

// ---------------- weight pre-convert f32 -> bf16 (once per launch) ----------------
// layout in wbf: Wa1[65536] | Wa2[65536] | W2[16384] | Wqkv[49152] | W3[16384]
__global__ __launch_bounds__(256) void k_prep(
        const float* __restrict__ Wa1, const float* __restrict__ Wa2,
        const float* __restrict__ W2, const float* __restrict__ Wqkv,
        const float* __restrict__ W3, ushort_t* __restrict__ wbf) {
    int i = blockIdx.x*256 + threadIdx.x;     // grid covers 212992 exactly
    float v;
    if (i < 65536)        v = Wa1[i];
    else if (i < 131072)  v = Wa2[i - 65536];
    else if (i < 147456)  v = W2[i - 131072];
    else if (i < 196608)  v = Wqkv[i - 147456];
    else                  v = W3[i - 196608];
    wbf[i] = f2bf(v);
}

// ---------------- fused linear1 + linear2 + to_qkv (MFMA, bf16 weights) ----------------
__global__ __launch_bounds__(256) void k_front(
        const float* __restrict__ x,
        const float* __restrict__ W1, const float* __restrict__ b1,
        const ushort_t* __restrict__ W2bf, const float* __restrict__ b2,
        const ushort_t* __restrict__ Wqkvbf,
        float* __restrict__ h, ushort_t* __restrict__ qf,
        ushort_t* __restrict__ kf, ushort_t* __restrict__ vf) {
    __shared__ __align__(16) char smem[16896];
    float* xs = (float*)(smem + 16384);
    int tid = threadIdx.x, w = tid >> 6, lane = tid & 63;
    int p0 = blockIdx.x * 32;

    if (tid < 96) xs[tid] = x[(size_t)p0*3 + tid];
    __syncthreads();

    // A: h = x@W1^T + b1 (f32 to global; bf16 swizzled LDS)
    #pragma unroll
    for (int it = 0; it < 16; ++it) {
        int lin = it*256 + tid;
        int m = lin >> 7, d = lin & 127;
        float hv = b1[d] + xs[m*3+0]*W1[d*3+0] + xs[m*3+1]*W1[d*3+1] + xs[m*3+2]*W1[d*3+2];
        h[(size_t)(p0+m)*DD + d] = hv;
        *(ushort_t*)&smem[SW256(m, d*2)] = f2bf(hv);
    }
    __syncthreads();

    // B: h1 = h@W2^T + b2 -> LDS @8192 (bf16 swizzled)
    {
        f32x4 acc[2][2];
        #pragma unroll
        for (int mt = 0; mt < 2; ++mt)
            #pragma unroll
            for (int ntl = 0; ntl < 2; ++ntl) acc[mt][ntl] = (f32x4){0,0,0,0};
        #pragma unroll
        for (int ks = 0; ks < 4; ++ks) {
            int k0 = ks*32 + (lane >> 4)*8;
            bf16x8 aF[2];
            #pragma unroll
            for (int mt = 0; mt < 2; ++mt)
                aF[mt] = *(const bf16x8*)&smem[SW256(mt*16 + (lane & 15), k0*2)];
            #pragma unroll
            for (int ntl = 0; ntl < 2; ++ntl) {
                int n = (2*w + ntl)*16 + (lane & 15);
                bf16x8 bF = *(const bf16x8*)&W2bf[(size_t)n*DD + k0];
                #pragma unroll
                for (int mt = 0; mt < 2; ++mt)
                    acc[mt][ntl] = __builtin_amdgcn_mfma_f32_16x16x32_bf16(aF[mt], bF, acc[mt][ntl], 0, 0, 0);
            }
        }
        #pragma unroll
        for (int ntl = 0; ntl < 2; ++ntl) {
            int n = (2*w + ntl)*16 + (lane & 15);
            float bias = b2[n];
            #pragma unroll
            for (int mt = 0; mt < 2; ++mt)
                #pragma unroll
                for (int i = 0; i < 4; ++i) {
                    int m = mt*16 + (lane >> 4)*4 + i;
                    *(ushort_t*)&smem[8192 + SW256(m, n*2)] = f2bf(acc[mt][ntl][i] + bias);
                }
        }
    }
    __syncthreads();

    // C: qkv = h1@Wqkv^T (N=384; wave w owns n-tiles w*6..w*6+5), bf16 out
    {
        f32x4 acc[2][6];
        #pragma unroll
        for (int mt = 0; mt < 2; ++mt)
            #pragma unroll
            for (int ntl = 0; ntl < 6; ++ntl) acc[mt][ntl] = (f32x4){0,0,0,0};
        #pragma unroll
        for (int ks = 0; ks < 4; ++ks) {
            int k0 = ks*32 + (lane >> 4)*8;
            bf16x8 aF[2];
            #pragma unroll
            for (int mt = 0; mt < 2; ++mt)
                aF[mt] = *(const bf16x8*)&smem[8192 + SW256(mt*16 + (lane & 15), k0*2)];
            #pragma unroll
            for (int ntl = 0; ntl < 6; ++ntl) {
                int n = (w*6 + ntl)*16 + (lane & 15);
                bf16x8 bF = *(const bf16x8*)&Wqkvbf[(size_t)n*DD + k0];
                #pragma unroll
                for (int mt = 0; mt < 2; ++mt)
                    acc[mt][ntl] = __builtin_amdgcn_mfma_f32_16x16x32_bf16(aF[mt], bF, acc[mt][ntl], 0, 0, 0);
            }
        }
        #pragma unroll
        for (int ntl = 0; ntl < 6; ++ntl) {
            int n = (w*6 + ntl)*16 + (lane & 15);
            int r = n >> 7, d = n & 127;
            ushort_t* dst = (r == 0) ? qf : (r == 1) ? kf : vf;
            #pragma unroll
            for (int mt = 0; mt < 2; ++mt)
                #pragma unroll
                for (int i = 0; i < 4; ++i) {
                    int m = mt*16 + (lane >> 4)*4 + i;
                    dst[(size_t)(p0+m)*DD + d] = f2bf(acc[mt][ntl][i]);
                }
        }
    }
}

// ---------------- KNN: one wave per query, register top-20 via packed keys ----------------
__global__ __launch_bounds__(256) void k_knn(const float* __restrict__ pos, int* __restrict__ idx) {
    int wid  = threadIdx.x >> 6;
    int lane = threadIdx.x & 63;
    int p = blockIdx.x*4 + wid;
    int b = p >> 12;
    float qx = pos[p*3+0], qy = pos[p*3+1], qz = pos[p*3+2];
    const float* pb = pos + (size_t)b*NN*3;

    uint32_t bk[KNB];
    #pragma unroll
    for (int i = 0; i < KNB; ++i) bk[i] = 0xFFFFFFFFu;

    for (int i = 0; i < NN/64; ++i) {
        int j = i*64 + lane;
        float dx = qx - pb[j*3+0];
        float dy = qy - pb[j*3+1];
        float dz = qz - pb[j*3+2];
        float d2 = dx*dx + dy*dy + dz*dz;
        uint32_t key = (__float_as_uint(d2) & 0xFFFFF000u) | (uint32_t)j;
        if (key < bk[KNB-1]) {
            uint32_t c = key;
            #pragma unroll
            for (int t = 0; t < KNB; ++t) {
                uint32_t lo = umin32(c, bk[t]);
                uint32_t hi = umax32(c, bk[t]);
                bk[t] = lo; c = hi;
            }
        }
    }
    for (int r = 0; r < KNB; ++r) {
        uint32_t m = bk[0];
        #pragma unroll
        for (int s = 1; s < 64; s <<= 1)
            m = umin32(m, (uint32_t)__shfl_xor((int)m, s, 64));
        if (lane == 0) idx[(size_t)p*KNB + r] = (int)(m & 0xFFFu);
        bool win = (bk[0] == m);
        #pragma unroll
        for (int t = 0; t < KNB-1; ++t) bk[t] = win ? bk[t+1] : bk[t];
        bk[KNB-1] = win ? 0xFFFFFFFFu : bk[KNB-1];
    }
}

// ---------------- fused pos-MLP + MFMA attn-MLP + softmax + aggregate ----------------
// LDS: XL bf16[80][128]swz @0 (20480) | TL bf16[80][64]swz @20480 (10240)
//      PH f32[80][8] @30720 (2560) | NIDX @33280 (320)
//      SIM bf16[80] stride 272B @0 (21760, union over dead XL/TL). Total 33600 B -> 4 blk/CU.
#define XL_OFF 0
#define TL_OFF 20480
#define PH_OFF 30720
#define NIDX_OFF 33280
#define SIM_STRIDE 272

__global__ __launch_bounds__(256, 4) void k_attn(
        const float* __restrict__ pos,
        const ushort_t* __restrict__ qf, const ushort_t* __restrict__ kf,
        const ushort_t* __restrict__ vf, const int* __restrict__ idx,
        const float* __restrict__ Wp1, const float* __restrict__ bp1,
        const float* __restrict__ Wp2, const float* __restrict__ bp2,
        const ushort_t* __restrict__ Wa1bf, const float* __restrict__ ba1,
        const ushort_t* __restrict__ Wa2bf, const float* __restrict__ ba2,
        float* __restrict__ agg) {
    __shared__ __align__(16) char smem[33600];
    float* phv  = (float*)(smem + PH_OFF);
    int*   nidx = (int*)(smem + NIDX_OFF);

    int tid = threadIdx.x, w = tid >> 6, lane = tid & 63;
    int p0 = blockIdx.x * 4, b = p0 >> 12;

    if (tid < 80) nidx[tid] = idx[(size_t)(p0 + tid/20)*KNB + (tid%20)];
    __syncthreads();

    // A1: pos-MLP hidden ph[m][jj]
    for (int lin = tid; lin < 80*PHH; lin += 256) {
        int m = lin >> 3, jj = lin & 7;
        int g = m / 20;
        int j = nidx[m];
        const float* pq = pos + (size_t)(p0 + g)*3;
        const float* pn = pos + (size_t)(b*NN + j)*3;
        float r0 = pq[0]-pn[0], r1 = pq[1]-pn[1], r2 = pq[2]-pn[2];
        float a = bp1[jj] + r0*Wp1[jj*3+0] + r1*Wp1[jj*3+1] + r2*Wp1[jj*3+2];
        phv[m*PHH + jj] = fmaxf(a, 0.f);
    }
    __syncthreads();

    // A2: X = q - k + pe -> XL bf16 swizzled (d fixed per thread; Wp2 row in regs)
    {
        int d = tid & 127;
        int mpar = tid >> 7;
        float4 wp2a = *(const float4*)(Wp2 + (size_t)d*PHH);
        float4 wp2b = *(const float4*)(Wp2 + (size_t)d*PHH + 4);
        float bp2d = bp2[d];
        float qv[4];
        #pragma unroll
        for (int g = 0; g < 4; ++g) qv[g] = bf2f(qf[(size_t)(p0+g)*DD + d]);
        #pragma unroll
        for (int g = 0; g < 4; ++g) {
            #pragma unroll
            for (int t = 0; t < 10; ++t) {
                int m = g*20 + mpar + 2*t;
                int j = nidx[m];
                float4 pa = *(const float4*)(phv + m*PHH);
                float4 pb = *(const float4*)(phv + m*PHH + 4);
                float pe = bp2d + pa.x*wp2a.x + pa.y*wp2a.y + pa.z*wp2a.z + pa.w*wp2a.w
                                + pb.x*wp2b.x + pb.y*wp2b.y + pb.z*wp2b.z + pb.w*wp2b.w;
                float kv = bf2f(kf[(size_t)(b*NN + j)*DD + d]);
                *(ushort_t*)&smem[XL_OFF + SW256(m, d*2)] = f2bf(qv[g] - kv + pe);
            }
        }
    }
    __syncthreads();

    // hidden dim in 8 chunks of 64; SIM accumulates in registers
    f32x4 accS[5][2];
    #pragma unroll
    for (int mt = 0; mt < 5; ++mt)
        #pragma unroll
        for (int ntl = 0; ntl < 2; ++ntl) accS[mt][ntl] = (f32x4){0,0,0,0};

    for (int c = 0; c < 8; ++c) {
        // B: T_chunk = relu(X @ Wa1_c^T + b); wave w owns 16 cols
        f32x4 accB[5];
        #pragma unroll
        for (int mt = 0; mt < 5; ++mt) accB[mt] = (f32x4){0,0,0,0};
        #pragma unroll
        for (int ks = 0; ks < 4; ++ks) {
            int k0 = ks*32 + (lane >> 4)*8;
            bf16x8 aF[5];
            #pragma unroll
            for (int mt = 0; mt < 5; ++mt)
                aF[mt] = *(const bf16x8*)&smem[XL_OFF + SW256(mt*16 + (lane & 15), k0*2)];
            bf16x8 bF = *(const bf16x8*)&Wa1bf[(size_t)(c*64 + w*16 + (lane & 15))*DD + k0];
            #pragma unroll
            for (int mt = 0; mt < 5; ++mt)
                accB[mt] = __builtin_amdgcn_mfma_f32_16x16x32_bf16(aF[mt], bF, accB[mt], 0, 0, 0);
        }
        {
            int al = w*16 + (lane & 15);
            float bias = ba1[c*64 + al];
            #pragma unroll
            for (int mt = 0; mt < 5; ++mt)
                #pragma unroll
                for (int i = 0; i < 4; ++i) {
                    int m = mt*16 + (lane >> 4)*4 + i;
                    *(ushort_t*)&smem[TL_OFF + SW128(m, al*2)] = f2bf(fmaxf(accB[mt][i] + bias, 0.f));
                }
        }
        __syncthreads();

        // C: SIM += T_chunk @ Wa2_c^T (K=64 for this chunk)
        #pragma unroll
        for (int ks = 0; ks < 2; ++ks) {
            int k0 = ks*32 + (lane >> 4)*8;
            bf16x8 aF[5];
            #pragma unroll
            for (int mt = 0; mt < 5; ++mt)
                aF[mt] = *(const bf16x8*)&smem[TL_OFF + SW128(mt*16 + (lane & 15), k0*2)];
            #pragma unroll
            for (int ntl = 0; ntl < 2; ++ntl) {
                int dd = w*32 + ntl*16 + (lane & 15);
                bf16x8 bF = *(const bf16x8*)&Wa2bf[(size_t)dd*AHH + c*64 + k0];
                #pragma unroll
                for (int mt = 0; mt < 5; ++mt)
                    accS[mt][ntl] = __builtin_amdgcn_mfma_f32_16x16x32_bf16(aF[mt], bF, accS[mt][ntl], 0, 0, 0);
            }
        }
        __syncthreads();
    }

    // SIM -> LDS bf16, padded stride (conflict-free)
    #pragma unroll
    for (int ntl = 0; ntl < 2; ++ntl) {
        int dd = w*32 + ntl*16 + (lane & 15);
        float bias2 = ba2[dd];
        #pragma unroll
        for (int mt = 0; mt < 5; ++mt)
            #pragma unroll
            for (int i = 0; i < 4; ++i) {
                int m = mt*16 + (lane >> 4)*4 + i;
                *(ushort_t*)&smem[m*SIM_STRIDE + dd*2] = f2bf(accS[mt][ntl][i] + bias2);
            }
    }
    __syncthreads();

    // D: softmax over kk (no max-subtract: |sim| ~ 1e-3) + aggregate; pe recomputed
    {
        int d = tid & 127;
        int g2 = tid >> 7;
        float4 wp2a = *(const float4*)(Wp2 + (size_t)d*PHH);
        float4 wp2b = *(const float4*)(Wp2 + (size_t)d*PHH + 4);
        float bp2d = bp2[d];
        #pragma unroll
        for (int gi = 0; gi < 2; ++gi) {
            int g = g2 + gi*2;
            float s = 0.f, anum = 0.f;
            #pragma unroll
            for (int kk = 0; kk < KNB; ++kk) {
                int m = g*20 + kk;
                int j = nidx[m];
                float sim = bf2f(*(const ushort_t*)&smem[m*SIM_STRIDE + d*2]);
                float4 pa = *(const float4*)(phv + m*PHH);
                float4 pb = *(const float4*)(phv + m*PHH + 4);
                float pe = bp2d + pa.x*wp2a.x + pa.y*wp2a.y + pa.z*wp2a.z + pa.w*wp2a.w
                                + pb.x*wp2b.x + pb.y*wp2b.y + pb.z*wp2b.z + pb.w*wp2b.w;
                float vv = bf2f(vf[(size_t)(b*NN + j)*DD + d]);
                float e = __expf(sim);
                anum += e * (vv + pe);
                s += e;
            }
            agg[(size_t)(p0 + g)*DD + d] = anum / s;
        }
    }
}

// ---------------- out = h + agg @ W3.T + b3 (MFMA, bf16 weights) ----------------
__global__ __launch_bounds__(256) void k_out(
        const float* __restrict__ agg, const float* __restrict__ h,
        const ushort_t* __restrict__ W3bf, const float* __restrict__ b3,
        float* __restrict__ out) {
    __shared__ __align__(16) char smem[8192];
    int tid = threadIdx.x, w = tid >> 6, lane = tid & 63;
    int p0 = blockIdx.x * 32;

    #pragma unroll
    for (int it = 0; it < 16; ++it) {
        int lin = it*256 + tid;
        int m = lin >> 7, d = lin & 127;
        *(ushort_t*)&smem[SW256(m, d*2)] = f2bf(agg[(size_t)(p0+m)*DD + d]);
    }
    __syncthreads();

    f32x4 acc[2][2];
    #pragma unroll
    for (int mt = 0; mt < 2; ++mt)
        #pragma unroll
        for (int ntl = 0; ntl < 2; ++ntl) acc[mt][ntl] = (f32x4){0,0,0,0};
    #pragma unroll
    for (int ks = 0; ks < 4; ++ks) {
        int k0 = ks*32 + (lane >> 4)*8;
        bf16x8 aF[2];
        #pragma unroll
        for (int mt = 0; mt < 2; ++mt)
            aF[mt] = *(const bf16x8*)&smem[SW256(mt*16 + (lane & 15), k0*2)];
        #pragma unroll
        for (int ntl = 0; ntl < 2; ++ntl) {
            int n = (2*w + ntl)*16 + (lane & 15);
            bf16x8 bF = *(const bf16x8*)&W3bf[(size_t)n*DD + k0];
            #pragma unroll
            for (int mt = 0; mt < 2; ++mt)
                acc[mt][ntl] = __builtin_amdgcn_mfma_f32_16x16x32_bf16(aF[mt], bF, acc[mt][ntl], 0, 0, 0);
        }
    }
    #pragma unroll
    for (int ntl = 0; ntl < 2; ++ntl) {
        int n = (2*w + ntl)*16 + (lane & 15);
        float bias = b3[n];
        #pragma unroll
        for (int mt = 0; mt < 2; ++mt)
            #pragma unroll
            for (int i = 0; i < 4; ++i) {
                int m = mt*16 + (lane >> 4)*4 + i;
                size_t o = (size_t)(p0+m)*DD + n;
                out[o] = acc[mt][ntl][i] + bias + h[o];
            }
    }
}

extern "C" void kernel_launch(void* const* d_in, const int* in_sizes, int n_in,
                              void* d_out, int out_size, void* d_ws, size_t ws_size,
                              hipStream_t stream) {
    const float* x    = (const float*)d_in[0];
    const float* pos  = (const float*)d_in[1];
    const float* W1   = (const float*)d_in[2];
    const float* b1   = (const float*)d_in[3];
    const float* W2   = (const float*)d_in[4];
    const float* b2   = (const float*)d_in[5];
    const float* W3   = (const float*)d_in[6];
    const float* b3   = (const float*)d_in[7];
    const float* Wqkv = (const float*)d_in[8];
    const float* Wp1  = (const float*)d_in[9];
    const float* bp1  = (const float*)d_in[10];
    const float* Wp2  = (const float*)d_in[11];
    const float* bp2  = (const float*)d_in[12];
    const float* Wa1  = (const float*)d_in[13];
    const float* ba1  = (const float*)d_in[14];
    const float* Wa2  = (const float*)d_in[15];
    const float* ba2  = (const float*)d_in[16];

    float* ws = (float*)d_ws;
    float* h   = ws;                                   // BN*DD f32
    float* agg = ws + (size_t)BN*DD;                   // BN*DD f32
    ushort_t* qf = (ushort_t*)(ws + 2*(size_t)BN*DD);  // 3 x BN*DD bf16
    ushort_t* kf = qf + (size_t)BN*DD;
    ushort_t* vf = qf + 2*(size_t)BN*DD;
    int* idx = (int*)((char*)d_ws + 14680064);         // BN*KNB int
    ushort_t* wbf = (ushort_t*)((char*)d_ws + 15335424);
    ushort_t* Wa1bf  = wbf;
    ushort_t* Wa2bf  = wbf + 65536;
    ushort_t* W2bf   = wbf + 131072;
    ushort_t* Wqkvbf = wbf + 147456;
    ushort_t* W3bf   = wbf + 196608;

    k_prep <<<832, 256, 0, stream>>>(Wa1, Wa2, W2, Wqkv, W3, wbf);
    k_front<<<BN/32, 256, 0, stream>>>(x, W1, b1, W2bf, b2, Wqkvbf, h, qf, kf, vf);
    k_knn  <<<BN/4, 256, 0, stream>>>(pos, idx);
    k_attn <<<BN/4, 256, 0, stream>>>(pos, qf, kf, vf, idx,
                                      Wp1, bp1, Wp2, bp2, Wa1bf, ba1, Wa2bf, ba2, agg);
    k_out  <<<BN/32, 256, 0, stream>>>(agg, h, W3bf, b3, (float*)d_out);
}

// Round 7
// 175.146 us; speedup vs baseline: 38.6126x; 1.0269x over previous
//
#include <hip/hip_runtime.h>
#include <stdint.h>

#define BB 2
#define NN 4096
#define KNB 20
#define DD 128
#define PHH 8
#define AHH 512
#define BN (BB*NN)

typedef unsigned short ushort_t;
typedef short bf16x8 __attribute__((ext_vector_type(8)));
typedef float f32x4 __attribute__((ext_vector_type(4)));

__device__ __forceinline__ uint32_t umin32(uint32_t a, uint32_t b) { return a < b ? a : b; }
__device__ __forceinline__ uint32_t umax32(uint32_t a, uint32_t b) { return a > b ? a : b; }

__device__ __forceinline__ ushort_t f2bf(float f) {   // RNE
    uint32_t x = __float_as_uint(f);
    return (ushort_t)((x + 0x7FFFu + ((x >> 16) & 1u)) >> 16);
}
__device__ __forceinline__ float bf2f(ushort_t u) {
    union { float f; uint32_t i; } c; c.i = ((uint32_t)u) << 16; return c.f;
}
__device__ __forceinline__ uint32_t cvt_pk_bf16(float lo, float hi) {
    uint32_t r;
    asm("v_cvt_pk_bf16_f32 %0, %1, %2" : "=v"(r) : "v"(lo), "v"(hi));
    return r;  // lo16 = bf16(lo), hi16 = bf16(hi)
}
__device__ __forceinline__ bf16x8 load_bfrag(const float* __restrict__ src) {
    float4 x = *(const float4*)src;
    float4 y = *(const float4*)(src + 4);
    union { bf16x8 v; uint32_t u[4]; } r;
    r.u[0] = cvt_pk_bf16(x.x, x.y);
    r.u[1] = cvt_pk_bf16(x.z, x.w);
    r.u[2] = cvt_pk_bf16(y.x, y.y);
    r.u[3] = cvt_pk_bf16(y.z, y.w);
    return r.v;
}

#define SW256(m, byteInRow) ((m)*256 + ((byteInRow) ^ (((m)&7) << 4)))
#define SW128(m, byteInRow) ((m)*128 + ((byteInRow) ^ (((m)&7) << 4)))

// ================= mega: knn(2048) || front(256) || prep(64) =================
__global__ __launch_bounds__(256) void k_mega(
        const float* __restrict__ x, const float* __restrict__ pos,
        const float* __restrict__ W1, const float* __restrict__ b1,
        const float* __restrict__ W2f, const float* __restrict__ b2,
        const float* __restrict__ Wqkvf,
        const float* __restrict__ Wa1, const float* __restrict__ Wa2,
        float* __restrict__ h, ushort_t* __restrict__ qf,
        ushort_t* __restrict__ kf, ushort_t* __restrict__ vf,
        int* __restrict__ idx, ushort_t* __restrict__ wbf) {
    __shared__ __align__(16) char smem[16896];
    int tid = threadIdx.x, w = tid >> 6, lane = tid & 63;
    int bid = blockIdx.x;

    if (bid < BN/4) {
        // ---------------- KNN: one wave per query ----------------
        int p = bid*4 + w;
        int b = p >> 12;
        float qx = pos[p*3+0], qy = pos[p*3+1], qz = pos[p*3+2];
        const float* pb = pos + (size_t)b*NN*3;
        uint32_t bk[KNB];
        #pragma unroll
        for (int i = 0; i < KNB; ++i) bk[i] = 0xFFFFFFFFu;
        for (int i = 0; i < NN/64; ++i) {
            int j = i*64 + lane;
            float dx = qx - pb[j*3+0];
            float dy = qy - pb[j*3+1];
            float dz = qz - pb[j*3+2];
            float d2 = dx*dx + dy*dy + dz*dz;
            uint32_t key = (__float_as_uint(d2) & 0xFFFFF000u) | (uint32_t)j;
            if (key < bk[KNB-1]) {
                uint32_t c = key;
                #pragma unroll
                for (int t = 0; t < KNB; ++t) {
                    uint32_t lo = umin32(c, bk[t]);
                    uint32_t hi = umax32(c, bk[t]);
                    bk[t] = lo; c = hi;
                }
            }
        }
        for (int r = 0; r < KNB; ++r) {
            uint32_t m = bk[0];
            #pragma unroll
            for (int s = 1; s < 64; s <<= 1)
                m = umin32(m, (uint32_t)__shfl_xor((int)m, s, 64));
            if (lane == 0) idx[(size_t)p*KNB + r] = (int)(m & 0xFFFu);
            bool win = (bk[0] == m);
            #pragma unroll
            for (int t = 0; t < KNB-1; ++t) bk[t] = win ? bk[t+1] : bk[t];
            bk[KNB-1] = win ? 0xFFFFFFFFu : bk[KNB-1];
        }
    } else if (bid < BN/4 + BN/32) {
        // ---------------- front: lin1 + lin2 + qkv (MFMA) ----------------
        float* xs = (float*)(smem + 16384);
        int p0 = (bid - BN/4) * 32;
        if (tid < 96) xs[tid] = x[(size_t)p0*3 + tid];
        __syncthreads();

        #pragma unroll
        for (int it = 0; it < 16; ++it) {
            int lin = it*256 + tid;
            int m = lin >> 7, d = lin & 127;
            float hv = b1[d] + xs[m*3+0]*W1[d*3+0] + xs[m*3+1]*W1[d*3+1] + xs[m*3+2]*W1[d*3+2];
            h[(size_t)(p0+m)*DD + d] = hv;
            *(ushort_t*)&smem[SW256(m, d*2)] = f2bf(hv);
        }
        __syncthreads();

        {   // h1 = h@W2^T + b2 -> LDS @8192
            f32x4 acc[2][2];
            #pragma unroll
            for (int mt = 0; mt < 2; ++mt)
                #pragma unroll
                for (int ntl = 0; ntl < 2; ++ntl) acc[mt][ntl] = (f32x4){0,0,0,0};
            #pragma unroll
            for (int ks = 0; ks < 4; ++ks) {
                int k0 = ks*32 + (lane >> 4)*8;
                bf16x8 aF[2];
                #pragma unroll
                for (int mt = 0; mt < 2; ++mt)
                    aF[mt] = *(const bf16x8*)&smem[SW256(mt*16 + (lane & 15), k0*2)];
                #pragma unroll
                for (int ntl = 0; ntl < 2; ++ntl) {
                    int n = (2*w + ntl)*16 + (lane & 15);
                    bf16x8 bF = load_bfrag(W2f + (size_t)n*DD + k0);
                    #pragma unroll
                    for (int mt = 0; mt < 2; ++mt)
                        acc[mt][ntl] = __builtin_amdgcn_mfma_f32_16x16x32_bf16(aF[mt], bF, acc[mt][ntl], 0, 0, 0);
                }
            }
            #pragma unroll
            for (int ntl = 0; ntl < 2; ++ntl) {
                int n = (2*w + ntl)*16 + (lane & 15);
                float bias = b2[n];
                #pragma unroll
                for (int mt = 0; mt < 2; ++mt)
                    #pragma unroll
                    for (int i = 0; i < 4; ++i) {
                        int m = mt*16 + (lane >> 4)*4 + i;
                        *(ushort_t*)&smem[8192 + SW256(m, n*2)] = f2bf(acc[mt][ntl][i] + bias);
                    }
            }
        }
        __syncthreads();

        {   // qkv = h1@Wqkv^T, bf16 out
            f32x4 acc[2][6];
            #pragma unroll
            for (int mt = 0; mt < 2; ++mt)
                #pragma unroll
                for (int ntl = 0; ntl < 6; ++ntl) acc[mt][ntl] = (f32x4){0,0,0,0};
            #pragma unroll
            for (int ks = 0; ks < 4; ++ks) {
                int k0 = ks*32 + (lane >> 4)*8;
                bf16x8 aF[2];
                #pragma unroll
                for (int mt = 0; mt < 2; ++mt)
                    aF[mt] = *(const bf16x8*)&smem[8192 + SW256(mt*16 + (lane & 15), k0*2)];
                #pragma unroll
                for (int ntl = 0; ntl < 6; ++ntl) {
                    int n = (w*6 + ntl)*16 + (lane & 15);
                    bf16x8 bF = load_bfrag(Wqkvf + (size_t)n*DD + k0);
                    #pragma unroll
                    for (int mt = 0; mt < 2; ++mt)
                        acc[mt][ntl] = __builtin_amdgcn_mfma_f32_16x16x32_bf16(aF[mt], bF, acc[mt][ntl], 0, 0, 0);
                }
            }
            #pragma unroll
            for (int ntl = 0; ntl < 6; ++ntl) {
                int n = (w*6 + ntl)*16 + (lane & 15);
                int r = n >> 7, d = n & 127;
                ushort_t* dst = (r == 0) ? qf : (r == 1) ? kf : vf;
                #pragma unroll
                for (int mt = 0; mt < 2; ++mt)
                    #pragma unroll
                    for (int i = 0; i < 4; ++i) {
                        int m = mt*16 + (lane >> 4)*4 + i;
                        dst[(size_t)(p0+m)*DD + d] = f2bf(acc[mt][ntl][i]);
                    }
            }
        }
    } else {
        // ---------------- prep: Wa1|Wa2 f32 -> bf16 ----------------
        int base = (bid - (BN/4 + BN/32)) * 2048 + tid * 8;
        const float* src = (base < 65536) ? (Wa1 + base) : (Wa2 + (base - 65536));
        union { ushort_t u[8]; uint4 q; } pk;
        #pragma unroll
        for (int i = 0; i < 8; ++i) pk.u[i] = f2bf(src[i]);
        *(uint4*)&wbf[base] = pk.q;
    }
}

// ======== attn: pe-MFMA + attn-MLP MFMA + in-register softmax/aggregate ========
// LDS: XL bf16[80][128]swz @0 (20480) | TL bf16[80][64]swz @20480 (10240)
//      PH bf16[80][8] @30720 (1280) | NIDX @32000 (320). Total 32320 -> 4-5 blk/CU.
#define XL_OFF 0
#define TL_OFF 20480
#define PH_OFF 30720
#define NIDX_OFF 32000

__global__ __launch_bounds__(256, 4) void k_attn(
        const float* __restrict__ pos,
        const ushort_t* __restrict__ qf, const ushort_t* __restrict__ kf,
        const ushort_t* __restrict__ vf, const int* __restrict__ idx,
        const float* __restrict__ Wp1, const float* __restrict__ bp1,
        const float* __restrict__ Wp2, const float* __restrict__ bp2,
        const ushort_t* __restrict__ Wa1bf, const float* __restrict__ ba1,
        const ushort_t* __restrict__ Wa2bf, const float* __restrict__ ba2,
        float* __restrict__ agg) {
    __shared__ __align__(16) char smem[32320];
    int* nidx = (int*)(smem + NIDX_OFF);

    int tid = threadIdx.x, w = tid >> 6, lane = tid & 63;
    int lg = lane >> 4, c16 = lane & 15;
    int p0 = blockIdx.x * 4, b = p0 >> 12;

    if (tid < 80) nidx[tid] = idx[(size_t)(p0 + tid/20)*KNB + (tid%20)];
    __syncthreads();

    // A1: pos-MLP hidden, one thread per m-row, packed bf16[8]
    if (tid < 80) {
        int m = tid, g = m / 20;
        int j = nidx[m];
        const float* pq = pos + (size_t)(p0+g)*3;
        const float* pn = pos + (size_t)(b*NN+j)*3;
        float r0 = pq[0]-pn[0], r1 = pq[1]-pn[1], r2 = pq[2]-pn[2];
        union { ushort_t u[8]; uint4 q; } pk;
        #pragma unroll
        for (int jj = 0; jj < PHH; ++jj) {
            float a = bp1[jj] + r0*Wp1[jj*3+0] + r1*Wp1[jj*3+1] + r2*Wp1[jj*3+2];
            pk.u[jj] = f2bf(fmaxf(a, 0.f));
        }
        *(uint4*)&smem[PH_OFF + m*16] = pk.q;
    }
    __syncthreads();

    int dA = w*32 + c16, dB = w*32 + 16 + c16;     // this lane's two d-columns
    float bp2A = bp2[dA], bp2B = bp2[dB];
    float ba2A = ba2[dA], ba2B = ba2[dB];

    // pe-MFMA B-fragments (K padded 8->32: only lg==0 lanes carry data)
    bf16x8 bP0 = {0,0,0,0,0,0,0,0}, bP1 = {0,0,0,0,0,0,0,0};
    if (lg == 0) {
        bP0 = load_bfrag(Wp2 + (size_t)dA*PHH);
        bP1 = load_bfrag(Wp2 + (size_t)dB*PHH);
    }

    float qv[4][2];
    #pragma unroll
    for (int g = 0; g < 4; ++g) {
        qv[g][0] = bf2f(qf[(size_t)(p0+g)*DD + dA]);
        qv[g][1] = bf2f(qf[(size_t)(p0+g)*DD + dB]);
    }

    uint32_t vpe_pk[5][4];   // (v+pe) packed bf16 pairs (dA,dB), [mt][i]

    // A2 fused with pe-MFMA, per m-tile
    #pragma unroll
    for (int mt = 0; mt < 5; ++mt) {
        bf16x8 aP = {0,0,0,0,0,0,0,0};
        if (lg == 0) aP = *(const bf16x8*)&smem[PH_OFF + (mt*16 + c16)*16];
        f32x4 accP0 = (f32x4){0,0,0,0}, accP1 = (f32x4){0,0,0,0};
        accP0 = __builtin_amdgcn_mfma_f32_16x16x32_bf16(aP, bP0, accP0, 0, 0, 0);
        accP1 = __builtin_amdgcn_mfma_f32_16x16x32_bf16(aP, bP1, accP1, 0, 0, 0);
        // q select: g(mt,lg) = [0, lg>=1, 1+(lg>=2), 2+(lg==3), 3]
        float qsA = (mt==0) ? qv[0][0]
                  : (mt==1) ? (lg>=1 ? qv[1][0] : qv[0][0])
                  : (mt==2) ? (lg>=2 ? qv[2][0] : qv[1][0])
                  : (mt==3) ? (lg==3 ? qv[3][0] : qv[2][0])
                  : qv[3][0];
        float qsB = (mt==0) ? qv[0][1]
                  : (mt==1) ? (lg>=1 ? qv[1][1] : qv[0][1])
                  : (mt==2) ? (lg>=2 ? qv[2][1] : qv[1][1])
                  : (mt==3) ? (lg==3 ? qv[3][1] : qv[2][1])
                  : qv[3][1];
        #pragma unroll
        for (int i = 0; i < 4; ++i) {
            int m = mt*16 + lg*4 + i;
            int j = nidx[m];
            const ushort_t* kr = kf + (size_t)(b*NN+j)*DD;
            const ushort_t* vr = vf + (size_t)(b*NN+j)*DD;
            float peA = accP0[i] + bp2A;
            float peB = accP1[i] + bp2B;
            *(ushort_t*)&smem[XL_OFF + SW256(m, dA*2)] = f2bf(qsA - bf2f(kr[dA]) + peA);
            *(ushort_t*)&smem[XL_OFF + SW256(m, dB*2)] = f2bf(qsB - bf2f(kr[dB]) + peB);
            vpe_pk[mt][i] = cvt_pk_bf16(bf2f(vr[dA]) + peA, bf2f(vr[dB]) + peB);
        }
    }
    __syncthreads();

    // attn-MLP: hidden in 8 chunks of 64; SIM accumulates in registers
    f32x4 accS[5][2];
    #pragma unroll
    for (int mt = 0; mt < 5; ++mt)
        #pragma unroll
        for (int ntl = 0; ntl < 2; ++ntl) accS[mt][ntl] = (f32x4){0,0,0,0};

    for (int c = 0; c < 8; ++c) {
        f32x4 accB[5];
        #pragma unroll
        for (int mt = 0; mt < 5; ++mt) accB[mt] = (f32x4){0,0,0,0};
        #pragma unroll
        for (int ks = 0; ks < 4; ++ks) {
            int k0 = ks*32 + lg*8;
            bf16x8 aF[5];
            #pragma unroll
            for (int mt = 0; mt < 5; ++mt)
                aF[mt] = *(const bf16x8*)&smem[XL_OFF + SW256(mt*16 + c16, k0*2)];
            bf16x8 bF = *(const bf16x8*)&Wa1bf[(size_t)(c*64 + w*16 + c16)*DD + k0];
            #pragma unroll
            for (int mt = 0; mt < 5; ++mt)
                accB[mt] = __builtin_amdgcn_mfma_f32_16x16x32_bf16(aF[mt], bF, accB[mt], 0, 0, 0);
        }
        {
            int al = w*16 + c16;
            float bias = ba1[c*64 + al];
            #pragma unroll
            for (int mt = 0; mt < 5; ++mt)
                #pragma unroll
                for (int i = 0; i < 4; ++i) {
                    int m = mt*16 + lg*4 + i;
                    *(ushort_t*)&smem[TL_OFF + SW128(m, al*2)] = f2bf(fmaxf(accB[mt][i] + bias, 0.f));
                }
        }
        __syncthreads();

        #pragma unroll
        for (int ks = 0; ks < 2; ++ks) {
            int k0 = ks*32 + lg*8;
            bf16x8 aF[5];
            #pragma unroll
            for (int mt = 0; mt < 5; ++mt)
                aF[mt] = *(const bf16x8*)&smem[TL_OFF + SW128(mt*16 + c16, k0*2)];
            #pragma unroll
            for (int ntl = 0; ntl < 2; ++ntl) {
                int dd = w*32 + ntl*16 + c16;
                bf16x8 bF = *(const bf16x8*)&Wa2bf[(size_t)dd*AHH + c*64 + k0];
                #pragma unroll
                for (int mt = 0; mt < 5; ++mt)
                    accS[mt][ntl] = __builtin_amdgcn_mfma_f32_16x16x32_bf16(aF[mt], bF, accS[mt][ntl], 0, 0, 0);
            }
        }
        __syncthreads();
    }

    // D: in-register softmax over kk + aggregate (no max-subtract: |sim| ~ 1e-3)
    float s_mtA[5], a_mtA[5], s_mtB[5], a_mtB[5];
    #pragma unroll
    for (int mt = 0; mt < 5; ++mt) {
        float sa = 0.f, aa = 0.f, sb = 0.f, ab = 0.f;
        #pragma unroll
        for (int i = 0; i < 4; ++i) {
            float eA = __expf(accS[mt][0][i] + ba2A);
            float eB = __expf(accS[mt][1][i] + ba2B);
            uint32_t pk = vpe_pk[mt][i];
            float vA = bf2f((ushort_t)(pk & 0xFFFFu));
            float vB = bf2f((ushort_t)(pk >> 16));
            sa += eA; aa += eA*vA;
            sb += eB; ab += eB*vB;
        }
        s_mtA[mt] = sa; a_mtA[mt] = aa; s_mtB[mt] = sb; a_mtB[mt] = ab;
    }
    bool eq0 = (lg==0), ge1 = (lg>=1), ge2 = (lg>=2), le1 = (lg<=1), le2 = (lg<=2), eq3 = (lg==3);
    float s0A = s_mtA[0] + (eq0 ? s_mtA[1] : 0.f);
    float s1A = (ge1 ? s_mtA[1] : 0.f) + (le1 ? s_mtA[2] : 0.f);
    float s2A = (ge2 ? s_mtA[2] : 0.f) + (le2 ? s_mtA[3] : 0.f);
    float s3A = (eq3 ? s_mtA[3] : 0.f) + s_mtA[4];
    float a0A = a_mtA[0] + (eq0 ? a_mtA[1] : 0.f);
    float a1A = (ge1 ? a_mtA[1] : 0.f) + (le1 ? a_mtA[2] : 0.f);
    float a2A = (ge2 ? a_mtA[2] : 0.f) + (le2 ? a_mtA[3] : 0.f);
    float a3A = (eq3 ? a_mtA[3] : 0.f) + a_mtA[4];
    float s0B = s_mtB[0] + (eq0 ? s_mtB[1] : 0.f);
    float s1B = (ge1 ? s_mtB[1] : 0.f) + (le1 ? s_mtB[2] : 0.f);
    float s2B = (ge2 ? s_mtB[2] : 0.f) + (le2 ? s_mtB[3] : 0.f);
    float s3B = (eq3 ? s_mtB[3] : 0.f) + s_mtB[4];
    float a0B = a_mtB[0] + (eq0 ? a_mtB[1] : 0.f);
    float a1B = (ge1 ? a_mtB[1] : 0.f) + (le1 ? a_mtB[2] : 0.f);
    float a2B = (ge2 ? a_mtB[2] : 0.f) + (le2 ? a_mtB[3] : 0.f);
    float a3B = (eq3 ? a_mtB[3] : 0.f) + a_mtB[4];

    #define RED2(v) { v += __shfl_xor(v, 16, 64); v += __shfl_xor(v, 32, 64); }
    RED2(s0A) RED2(s1A) RED2(s2A) RED2(s3A)
    RED2(a0A) RED2(a1A) RED2(a2A) RED2(a3A)
    RED2(s0B) RED2(s1B) RED2(s2B) RED2(s3B)
    RED2(a0B) RED2(a1B) RED2(a2B) RED2(a3B)
    #undef RED2

    float myS_A = (lg==0) ? s0A : (lg==1) ? s1A : (lg==2) ? s2A : s3A;
    float myA_A = (lg==0) ? a0A : (lg==1) ? a1A : (lg==2) ? a2A : a3A;
    float myS_B = (lg==0) ? s0B : (lg==1) ? s1B : (lg==2) ? s2B : s3B;
    float myA_B = (lg==0) ? a0B : (lg==1) ? a1B : (lg==2) ? a2B : a3B;
    agg[(size_t)(p0+lg)*DD + dA] = myA_A / myS_A;
    agg[(size_t)(p0+lg)*DD + dB] = myA_B / myS_B;
}

// ---------------- out = h + agg @ W3.T + b3 (MFMA) ----------------
__global__ __launch_bounds__(256) void k_out(
        const float* __restrict__ agg, const float* __restrict__ h,
        const float* __restrict__ W3f, const float* __restrict__ b3,
        float* __restrict__ out) {
    __shared__ __align__(16) char smem[8192];
    int tid = threadIdx.x, w = tid >> 6, lane = tid & 63;
    int p0 = blockIdx.x * 32;

    #pragma unroll
    for (int it = 0; it < 16; ++it) {
        int lin = it*256 + tid;
        int m = lin >> 7, d = lin & 127;
        *(ushort_t*)&smem[SW256(m, d*2)] = f2bf(agg[(size_t)(p0+m)*DD + d]);
    }
    __syncthreads();

    f32x4 acc[2][2];
    #pragma unroll
    for (int mt = 0; mt < 2; ++mt)
        #pragma unroll
        for (int ntl = 0; ntl < 2; ++ntl) acc[mt][ntl] = (f32x4){0,0,0,0};
    #pragma unroll
    for (int ks = 0; ks < 4; ++ks) {
        int k0 = ks*32 + (lane >> 4)*8;
        bf16x8 aF[2];
        #pragma unroll
        for (int mt = 0; mt < 2; ++mt)
            aF[mt] = *(const bf16x8*)&smem[SW256(mt*16 + (lane & 15), k0*2)];
        #pragma unroll
        for (int ntl = 0; ntl < 2; ++ntl) {
            int n = (2*w + ntl)*16 + (lane & 15);
            bf16x8 bF = load_bfrag(W3f + (size_t)n*DD + k0);
            #pragma unroll
            for (int mt = 0; mt < 2; ++mt)
                acc[mt][ntl] = __builtin_amdgcn_mfma_f32_16x16x32_bf16(aF[mt], bF, acc[mt][ntl], 0, 0, 0);
        }
    }
    #pragma unroll
    for (int ntl = 0; ntl < 2; ++ntl) {
        int n = (2*w + ntl)*16 + (lane & 15);
        float bias = b3[n];
        #pragma unroll
        for (int mt = 0; mt < 2; ++mt)
            #pragma unroll
            for (int i = 0; i < 4; ++i) {
                int m = mt*16 + (lane >> 4)*4 + i;
                size_t o = (size_t)(p0+m)*DD + n;
                out[o] = acc[mt][ntl][i] + bias + h[o];
            }
    }
}

extern "C" void kernel_launch(void* const* d_in, const int* in_sizes, int n_in,
                              void* d_out, int out_size, void* d_ws, size_t ws_size,
                              hipStream_t stream) {
    const float* x    = (const float*)d_in[0];
    const float* pos  = (const float*)d_in[1];
    const float* W1   = (const float*)d_in[2];
    const float* b1   = (const float*)d_in[3];
    const float* W2   = (const float*)d_in[4];
    const float* b2   = (const float*)d_in[5];
    const float* W3   = (const float*)d_in[6];
    const float* b3   = (const float*)d_in[7];
    const float* Wqkv = (const float*)d_in[8];
    const float* Wp1  = (const float*)d_in[9];
    const float* bp1  = (const float*)d_in[10];
    const float* Wp2  = (const float*)d_in[11];
    const float* bp2  = (const float*)d_in[12];
    const float* Wa1  = (const float*)d_in[13];
    const float* ba1  = (const float*)d_in[14];
    const float* Wa2  = (const float*)d_in[15];
    const float* ba2  = (const float*)d_in[16];

    float* ws = (float*)d_ws;
    float* h   = ws;                                   // BN*DD f32
    float* agg = ws + (size_t)BN*DD;                   // BN*DD f32
    ushort_t* qf = (ushort_t*)(ws + 2*(size_t)BN*DD);  // 3 x BN*DD bf16
    ushort_t* kf = qf + (size_t)BN*DD;
    ushort_t* vf = qf + 2*(size_t)BN*DD;
    int* idx = (int*)((char*)d_ws + 14680064);         // BN*KNB int
    ushort_t* wbf = (ushort_t*)((char*)d_ws + 15335424);
    ushort_t* Wa1bf = wbf;
    ushort_t* Wa2bf = wbf + 65536;

    k_mega<<<BN/4 + BN/32 + 64, 256, 0, stream>>>(x, pos, W1, b1, W2, b2, Wqkv,
                                                  Wa1, Wa2, h, qf, kf, vf, idx, wbf);
    k_attn<<<BN/4, 256, 0, stream>>>(pos, qf, kf, vf, idx,
                                     Wp1, bp1, Wp2, bp2, Wa1bf, ba1, Wa2bf, ba2, agg);
    k_out <<<BN/32, 256, 0, stream>>>(agg, h, W3, b3, (float*)d_out);
}